// Round 1
// baseline (506.311 us; speedup 1.0000x reference)
//
#include <hip/hip_runtime.h>
#include <math.h>

#define SF 16
#define ED 32
#define LTOK 20
#define DIN 176
#define HC 128

static __device__ __forceinline__ float leaky02(float x) { return x >= 0.f ? x : 0.2f * x; }
static __device__ __forceinline__ float eluf(float x)    { return x > 0.f ? x : expm1f(x); }

// ---------- 1. features (masked-mean embeddings + scalars) + LayerNorm ----------
__global__ __launch_bounds__(256)
void feat_ln_kernel(const float* __restrict__ xs,
                    const int* __restrict__ i0, const int* __restrict__ i1,
                    const int* __restrict__ i2, const int* __restrict__ i3,
                    const int* __restrict__ i4,
                    const float* __restrict__ e0, const float* __restrict__ e1,
                    const float* __restrict__ e2, const float* __restrict__ e3,
                    const float* __restrict__ e4,
                    const float* __restrict__ g, const float* __restrict__ b,
                    float* __restrict__ out, int N)
{
  int n = blockIdx.x;
  int t = threadIdx.x;
  __shared__ int toks[5 * LTOK];
  __shared__ float red[2][4];
  if (t < 5 * LTOK) {
    int f = t / LTOK, j = t - f * LTOK;
    const int* ip = (f == 0) ? i0 : (f == 1) ? i1 : (f == 2) ? i2 : (f == 3) ? i3 : i4;
    toks[t] = ip[n * LTOK + j];
  }
  __syncthreads();
  float v = 0.f;
  if (t < SF) {
    v = xs[n * SF + t];
  } else if (t < DIN) {
    int f = (t - SF) >> 5;
    int c = (t - SF) & 31;
    const float* ep = (f == 0) ? e0 : (f == 1) ? e1 : (f == 2) ? e2 : (f == 3) ? e3 : e4;
    float sum = 0.f, cnt = 0.f;
    #pragma unroll
    for (int j = 0; j < LTOK; ++j) {
      int idx = toks[f * LTOK + j];
      if (idx != 0) { sum += ep[idx * ED + c]; cnt += 1.f; }
    }
    v = sum / (cnt + 1e-9f);
  }
  float p  = (t < DIN) ? v : 0.f;
  float p2 = p * p;
  #pragma unroll
  for (int off = 32; off; off >>= 1) { p += __shfl_down(p, off); p2 += __shfl_down(p2, off); }
  int wv = t >> 6, lane = t & 63;
  if (lane == 0) { red[0][wv] = p; red[1][wv] = p2; }
  __syncthreads();
  float tot  = red[0][0] + red[0][1] + red[0][2] + red[0][3];
  float tot2 = red[1][0] + red[1][1] + red[1][2] + red[1][3];
  float mu   = tot * (1.f / DIN);
  float var  = fmaxf(tot2 * (1.f / DIN) - mu * mu, 0.f);
  float rstd = rsqrtf(var + 1e-5f);
  if (t < DIN) out[n * DIN + t] = (v - mu) * rstd * g[t] + b[t];
}

// ---------- 2. fp32 tiled GEMM: C[M,Nc] = A[M,K] @ B[K,Nc] ----------
#define BM 64
#define BN 64
#define BK 16
#define PADW 4
__global__ __launch_bounds__(256)
void gemm_kernel(const float* __restrict__ A, const float* __restrict__ B,
                 float* __restrict__ C, int M, int K, int Nc)
{
  __shared__ __align__(16) float As[BK][BM + PADW];
  __shared__ __align__(16) float Bs[BK][BN + PADW];
  int tid = threadIdx.x;
  int bm = blockIdx.y * BM;
  int bn = blockIdx.x * BN;
  int tr = tid >> 4, tc = tid & 15;
  int aRow = tid >> 2, aK = (tid & 3) << 2;
  int bK = tid >> 4, bN = (tid & 15) << 2;
  float acc[4][4] = {};
  for (int k0 = 0; k0 < K; k0 += BK) {
    int gm = bm + aRow;
    float4 av;
    if (gm < M) av = *(const float4*)&A[gm * K + k0 + aK];
    else        av = make_float4(0.f, 0.f, 0.f, 0.f);
    As[aK + 0][aRow] = av.x; As[aK + 1][aRow] = av.y;
    As[aK + 2][aRow] = av.z; As[aK + 3][aRow] = av.w;
    *(float4*)&Bs[bK][bN] = *(const float4*)&B[(k0 + bK) * Nc + bn + bN];
    __syncthreads();
    #pragma unroll
    for (int k = 0; k < BK; ++k) {
      float4 a  = *(const float4*)&As[k][tr << 2];
      float4 bv = *(const float4*)&Bs[k][tc << 2];
      float ar[4] = {a.x, a.y, a.z, a.w};
      float br[4] = {bv.x, bv.y, bv.z, bv.w};
      #pragma unroll
      for (int i = 0; i < 4; ++i)
        #pragma unroll
        for (int j = 0; j < 4; ++j)
          acc[i][j] += ar[i] * br[j];
    }
    __syncthreads();
  }
  #pragma unroll
  for (int i = 0; i < 4; ++i) {
    int row = bm + (tr << 2) + i;
    if (row < M) {
      float4 o = make_float4(acc[i][0], acc[i][1], acc[i][2], acc[i][3]);
      *(float4*)&C[row * Nc + bn + (tc << 2)] = o;
    }
  }
}

// ---------- 3. attention logits: al_s[n,h] = sum_c H[n,h,c]*a_s[h,c] ----------
template<int HH>
__global__ __launch_bounds__(128)
void logits_kernel(const float* __restrict__ H,
                   const float* __restrict__ a_s, const float* __restrict__ a_d,
                   float* __restrict__ al_s, float* __restrict__ al_d, int N)
{
  int n = blockIdx.x, t = threadIdx.x;
  int wv = t >> 6, lane = t & 63;
  __shared__ float tmp[2][2];
  #pragma unroll
  for (int h = 0; h < HH; ++h) {
    float hv = H[n * HH * HC + h * HC + t];
    float ps = hv * a_s[h * HC + t];
    float pd = hv * a_d[h * HC + t];
    #pragma unroll
    for (int off = 32; off; off >>= 1) { ps += __shfl_down(ps, off); pd += __shfl_down(pd, off); }
    if (lane == 0) { tmp[0][wv] = ps; tmp[1][wv] = pd; }
    __syncthreads();
    if (t == 0) {
      al_s[n * HH + h] = tmp[0][0] + tmp[0][1];
      al_d[n * HH + h] = tmp[1][0] + tmp[1][1];
    }
    __syncthreads();
  }
}

// ---------- 4. CSR build ----------
__global__ void zero_kernel(int* __restrict__ p, int n)
{
  int i = blockIdx.x * blockDim.x + threadIdx.x;
  if (i < n) p[i] = 0;
}

__global__ void count_kernel(const int* __restrict__ ei, int E, int N, int* __restrict__ deg)
{
  int e = blockIdx.x * blockDim.x + threadIdx.x;
  if (e < E + N) {
    int dst = (e < E) ? ei[E + e] : (e - E);
    atomicAdd(&deg[dst], 1);
  }
}

__global__ __launch_bounds__(1024)
void scan_kernel(const int* __restrict__ deg, int* __restrict__ rowptr,
                 int* __restrict__ fill, int N)
{
  __shared__ int sums[1024];
  int t = threadIdx.x;
  int CH = (N + 1023) >> 10;
  int base = t * CH;
  int s = 0;
  for (int i = 0; i < CH; ++i) if (base + i < N) s += deg[base + i];
  sums[t] = s;
  __syncthreads();
  for (int off = 1; off < 1024; off <<= 1) {
    int v = (t >= off) ? sums[t - off] : 0;
    __syncthreads();
    sums[t] += v;
    __syncthreads();
  }
  int run = sums[t] - s;  // exclusive prefix
  for (int i = 0; i < CH; ++i) {
    if (base + i < N) {
      rowptr[base + i] = run;
      fill[base + i]   = run;
      run += deg[base + i];
    }
  }
  if (t == 1023) rowptr[N] = run;
}

__global__ void scatter_kernel(const int* __restrict__ ei, int E, int N,
                               int* __restrict__ fill, int* __restrict__ csr_src)
{
  int e = blockIdx.x * blockDim.x + threadIdx.x;
  if (e < E + N) {
    int src, dst;
    if (e < E) { src = ei[e]; dst = ei[E + e]; }
    else       { src = dst = e - E; }
    int pos = atomicAdd(&fill[dst], 1);
    csr_src[pos] = src;
  }
}

// ---------- 5. per-dst softmax + aggregate + bias + ELU ----------
template<int HH>
__global__ __launch_bounds__(HH * 64)
void agg_kernel(const float* __restrict__ H,
                const float* __restrict__ al_s, const float* __restrict__ al_d,
                const int* __restrict__ rowptr, const int* __restrict__ csr_src,
                const float* __restrict__ bias, float* __restrict__ out, int N)
{
  int n = blockIdx.x;
  int h = threadIdx.x >> 6;
  int lane = threadIdx.x & 63;
  int rs = rowptr[n], re = rowptr[n + 1];
  float ald = al_d[n * HH + h];

  // online (max, sum) per lane
  float m = -1e30f, s = 0.f;
  for (int i = rs + lane; i < re; i += 64) {
    int src = csr_src[i];
    float e = leaky02(al_s[src * HH + h] + ald);
    float Mx = fmaxf(m, e);
    s = s * __expf(m - Mx) + __expf(e - Mx);
    m = Mx;
  }
  #pragma unroll
  for (int off = 32; off; off >>= 1) {
    float m2 = __shfl_down(m, off);
    float s2 = __shfl_down(s, off);
    float Mx = fmaxf(m, m2);
    s = s * __expf(m - Mx) + s2 * __expf(m2 - Mx);
    m = Mx;
  }
  m = __shfl(m, 0);
  s = __shfl(s, 0);
  float inv_den = 1.f / (s + 1e-16f);

  float acc0 = 0.f, acc1 = 0.f;
  for (int i = rs; i < re; ++i) {
    int src = csr_src[i];
    float e = leaky02(al_s[src * HH + h] + ald);
    float wgt = __expf(e - m) * inv_den;
    const float* hp = &H[src * HH * HC + h * HC];
    acc0 += wgt * hp[lane];
    acc1 += wgt * hp[lane + 64];
  }
  float o0 = eluf(acc0 + bias[h * HC + lane]);
  float o1 = eluf(acc1 + bias[h * HC + lane + 64]);
  out[n * HH * HC + h * HC + lane]      = o0;
  out[n * HH * HC + h * HC + lane + 64] = o1;
}

// ---------- 6. global max pool ----------
static __device__ __forceinline__ unsigned enc_f(float f)
{
  unsigned u = __float_as_uint(f);
  return (u & 0x80000000u) ? ~u : (u | 0x80000000u);
}
static __device__ __forceinline__ float dec_f(unsigned u)
{
  return (u & 0x80000000u) ? __uint_as_float(u & 0x7fffffffu) : __uint_as_float(~u);
}

__global__ void pool_init_kernel(unsigned* __restrict__ p, int n)
{
  int i = blockIdx.x * blockDim.x + threadIdx.x;
  if (i < n) p[i] = 0x00800000u;  // enc(-FLT_MAX)
}

__global__ void pool_scatter_kernel(const float* __restrict__ x, const int* __restrict__ batch,
                                    unsigned* __restrict__ pool, int N)
{
  int i = blockIdx.x * blockDim.x + threadIdx.x;
  if (i < N * HC) {
    int n = i >> 7, c = i & (HC - 1);
    atomicMax(&pool[batch[n] * HC + c], enc_f(x[i]));
  }
}

__global__ void pool_final_kernel(const unsigned* __restrict__ pool, float* __restrict__ out, int n)
{
  int i = blockIdx.x * blockDim.x + threadIdx.x;
  if (i < n) out[i] = dec_f(pool[i]);
}

// ---------- launch ----------
extern "C" void kernel_launch(void* const* d_in, const int* in_sizes, int n_in,
                              void* d_out, int out_size, void* d_ws, size_t ws_size,
                              hipStream_t stream)
{
  const float* x_scalar = (const float*)d_in[0];
  const int* i0 = (const int*)d_in[1];
  const int* i1 = (const int*)d_in[2];
  const int* i2 = (const int*)d_in[3];
  const int* i3 = (const int*)d_in[4];
  const int* i4 = (const int*)d_in[5];
  const int* ei = (const int*)d_in[6];
  const int* batch = (const int*)d_in[7];
  const float* e0 = (const float*)d_in[8];
  const float* e1 = (const float*)d_in[9];
  const float* e2 = (const float*)d_in[10];
  const float* e3 = (const float*)d_in[11];
  const float* e4 = (const float*)d_in[12];
  const float* ln_g = (const float*)d_in[13];
  const float* ln_b = (const float*)d_in[14];
  const float* W1 = (const float*)d_in[15];
  const float* as1 = (const float*)d_in[16];
  const float* ad1 = (const float*)d_in[17];
  const float* b1 = (const float*)d_in[18];
  const float* W2 = (const float*)d_in[19];
  const float* as2 = (const float*)d_in[20];
  const float* ad2 = (const float*)d_in[21];
  const float* b2 = (const float*)d_in[22];

  const int N  = in_sizes[0] / SF;
  const int E  = in_sizes[6] / 2;
  const int Et = E + N;
  const int Bg = out_size / HC;

  char* w = (char*)d_ws;
  auto alloc = [&](size_t bytes) -> char* {
    char* p = w;
    w += (bytes + 255) & ~(size_t)255;
    return p;
  };
  float* feats   = (float*)alloc((size_t)N * DIN * 4);
  float* H1      = (float*)alloc((size_t)N * 512 * 4);
  float* X2      = (float*)alloc((size_t)N * 512 * 4);
  float* als1    = (float*)alloc((size_t)N * 4 * 4);
  float* ald1    = (float*)alloc((size_t)N * 4 * 4);
  float* als2    = (float*)alloc((size_t)N * 4);
  float* ald2    = (float*)alloc((size_t)N * 4);
  int*   deg     = (int*)alloc((size_t)N * 4);
  int*   rowptr  = (int*)alloc((size_t)(N + 1) * 4);
  int*   fill    = (int*)alloc((size_t)N * 4);
  int*   csr_src = (int*)alloc((size_t)Et * 4);
  unsigned* pool = (unsigned*)alloc((size_t)Bg * HC * 4);
  // region reuse (lifetimes disjoint): H2 over feats, X3 over H1
  float* H2 = feats;   // N*128 <= N*176
  float* X3 = H1;      // N*128 <= N*512

  feat_ln_kernel<<<N, 256, 0, stream>>>(x_scalar, i0, i1, i2, i3, i4,
                                        e0, e1, e2, e3, e4, ln_g, ln_b, feats, N);
  gemm_kernel<<<dim3(512 / BN, (N + BM - 1) / BM), 256, 0, stream>>>(feats, W1, H1, N, DIN, 512);
  logits_kernel<4><<<N, 128, 0, stream>>>(H1, as1, ad1, als1, ald1, N);

  zero_kernel<<<(N + 255) / 256, 256, 0, stream>>>(deg, N);
  count_kernel<<<(Et + 255) / 256, 256, 0, stream>>>(ei, E, N, deg);
  scan_kernel<<<1, 1024, 0, stream>>>(deg, rowptr, fill, N);
  scatter_kernel<<<(Et + 255) / 256, 256, 0, stream>>>(ei, E, N, fill, csr_src);

  agg_kernel<4><<<N, 256, 0, stream>>>(H1, als1, ald1, rowptr, csr_src, b1, X2, N);
  gemm_kernel<<<dim3(HC / BN, (N + BM - 1) / BM), 256, 0, stream>>>(X2, W2, H2, N, 512, HC);
  logits_kernel<1><<<N, 128, 0, stream>>>(H2, as2, ad2, als2, ald2, N);
  agg_kernel<1><<<N, 64, 0, stream>>>(H2, als2, ald2, rowptr, csr_src, b2, X3, N);

  pool_init_kernel<<<(Bg * HC + 255) / 256, 256, 0, stream>>>(pool, Bg * HC);
  pool_scatter_kernel<<<(N * HC + 255) / 256, 256, 0, stream>>>(X3, batch, pool, N);
  pool_final_kernel<<<(Bg * HC + 255) / 256, 256, 0, stream>>>(pool, (float*)d_out, Bg * HC);
}

// Round 2
// 437.053 us; speedup vs baseline: 1.1585x; 1.1585x over previous
//
#include <hip/hip_runtime.h>
#include <math.h>

#define SF 16
#define ED 32
#define LTOK 20
#define DIN 176
#define KP1 192   // DIN padded to multiple of 32
#define HC 128

typedef short bf16x8 __attribute__((ext_vector_type(8)));
typedef float f32x4 __attribute__((ext_vector_type(4)));

static __device__ __forceinline__ float leaky02(float x) { return x >= 0.f ? x : 0.2f * x; }
static __device__ __forceinline__ float eluf(float x)    { return x > 0.f ? x : expm1f(x); }
static __device__ __forceinline__ float b2f(unsigned short u) { return __uint_as_float(((unsigned)u) << 16); }
static __device__ __forceinline__ unsigned short f2b(float f)
{
  unsigned u = __float_as_uint(f);
  return (unsigned short)((u + 0x7fffu + ((u >> 16) & 1u)) >> 16);
}

// ---------- 1. features (masked-mean embeddings + scalars) + LayerNorm -> bf16 [N][KP1] ----------
__global__ __launch_bounds__(256)
void feat_ln_kernel(const float* __restrict__ xs,
                    const int* __restrict__ i0, const int* __restrict__ i1,
                    const int* __restrict__ i2, const int* __restrict__ i3,
                    const int* __restrict__ i4,
                    const float* __restrict__ e0, const float* __restrict__ e1,
                    const float* __restrict__ e2, const float* __restrict__ e3,
                    const float* __restrict__ e4,
                    const float* __restrict__ g, const float* __restrict__ b,
                    unsigned short* __restrict__ out, int N)
{
  int n = blockIdx.x;
  int t = threadIdx.x;
  __shared__ int toks[5 * LTOK];
  __shared__ float red[2][4];
  if (t < 5 * LTOK) {
    int f = t / LTOK, j = t - f * LTOK;
    const int* ip = (f == 0) ? i0 : (f == 1) ? i1 : (f == 2) ? i2 : (f == 3) ? i3 : i4;
    toks[t] = ip[n * LTOK + j];
  }
  __syncthreads();
  float v = 0.f;
  if (t < SF) {
    v = xs[n * SF + t];
  } else if (t < DIN) {
    int f = (t - SF) >> 5;
    int c = (t - SF) & 31;
    const float* ep = (f == 0) ? e0 : (f == 1) ? e1 : (f == 2) ? e2 : (f == 3) ? e3 : e4;
    float sum = 0.f, cnt = 0.f;
    #pragma unroll
    for (int j = 0; j < LTOK; ++j) {
      int idx = toks[f * LTOK + j];
      if (idx != 0) { sum += ep[idx * ED + c]; cnt += 1.f; }
    }
    v = sum / (cnt + 1e-9f);
  }
  float p  = (t < DIN) ? v : 0.f;
  float p2 = p * p;
  #pragma unroll
  for (int off = 32; off; off >>= 1) { p += __shfl_down(p, off); p2 += __shfl_down(p2, off); }
  int wv = t >> 6, lane = t & 63;
  if (lane == 0) { red[0][wv] = p; red[1][wv] = p2; }
  __syncthreads();
  float tot  = red[0][0] + red[0][1] + red[0][2] + red[0][3];
  float tot2 = red[1][0] + red[1][1] + red[1][2] + red[1][3];
  float mu   = tot * (1.f / DIN);
  float var  = fmaxf(tot2 * (1.f / DIN) - mu * mu, 0.f);
  float rstd = rsqrtf(var + 1e-5f);
  if (t < DIN)      out[n * KP1 + t] = f2b((v - mu) * rstd * g[t] + b[t]);
  else if (t < KP1) out[n * KP1 + t] = 0;
}

// ---------- 2. pack W [K][Nc] fp32 -> Wt [Nc][KPad] bf16 (zero pad) ----------
__global__ void pack_wt_kernel(const float* __restrict__ W, unsigned short* __restrict__ Wt,
                               int K, int Nc, int KPad)
{
  int i = blockIdx.x * blockDim.x + threadIdx.x;
  if (i < Nc * KPad) {
    int n = i / KPad;
    int k = i - n * KPad;
    float v = (k < K) ? W[(size_t)k * Nc + n] : 0.f;
    Wt[i] = f2b(v);
  }
}

// ---------- 3. MFMA bf16 GEMM: C[M,Nc] = A[M,KPad] @ Bt[Nc,KPad]^T, bf16 out ----------
// 128x128 tile, 4 waves (2x2), each 64x64 via 4x4 frags of 16x16x32.
// LDS kc-major [4][128][8]: frag reads are 16 consecutive 16B chunks per lane-group -> conflict-free.
template<int KPad>
__global__ __launch_bounds__(256)
void gemm_bf16_kernel(const unsigned short* __restrict__ A, const unsigned short* __restrict__ Bt,
                      unsigned short* __restrict__ C, int M, int Nc)
{
  __shared__ __align__(16) unsigned short As[4][128][8];
  __shared__ __align__(16) unsigned short Bs[4][128][8];
  int tid  = threadIdx.x;
  int lane = tid & 63, wave = tid >> 6;
  int wm = (wave >> 1) << 6, wn = (wave & 1) << 6;
  int bm = blockIdx.y << 7, bn = blockIdx.x << 7;

  int srow = tid >> 1;            // 0..127
  int skc  = (tid & 1) << 1;      // 0 or 2
  const unsigned short* Arow = A  + (size_t)(bm + srow) * KPad + skc * 8;
  const unsigned short* Brow = Bt + (size_t)(bn + srow) * KPad + skc * 8;
  bool aok = (bm + srow) < M;

  f32x4 acc[4][4];
  #pragma unroll
  for (int m = 0; m < 4; ++m)
    #pragma unroll
    for (int n2 = 0; n2 < 4; ++n2) acc[m][n2] = (f32x4){0.f, 0.f, 0.f, 0.f};

  int kc  = lane >> 4;
  int r16 = lane & 15;

  for (int k0 = 0; k0 < KPad; k0 += 32) {
    int4 av0 = make_int4(0, 0, 0, 0), av1 = make_int4(0, 0, 0, 0);
    if (aok) {
      av0 = *(const int4*)(Arow + k0);
      av1 = *(const int4*)(Arow + k0 + 8);
    }
    int4 bv0 = *(const int4*)(Brow + k0);
    int4 bv1 = *(const int4*)(Brow + k0 + 8);
    __syncthreads();
    *(int4*)&As[skc][srow][0]     = av0;
    *(int4*)&As[skc + 1][srow][0] = av1;
    *(int4*)&Bs[skc][srow][0]     = bv0;
    *(int4*)&Bs[skc + 1][srow][0] = bv1;
    __syncthreads();

    bf16x8 af[4], bfr[4];
    #pragma unroll
    for (int m = 0; m < 4; ++m)  af[m]  = *(const bf16x8*)&As[kc][wm + m * 16 + r16][0];
    #pragma unroll
    for (int n2 = 0; n2 < 4; ++n2) bfr[n2] = *(const bf16x8*)&Bs[kc][wn + n2 * 16 + r16][0];
    #pragma unroll
    for (int m = 0; m < 4; ++m)
      #pragma unroll
      for (int n2 = 0; n2 < 4; ++n2)
        acc[m][n2] = __builtin_amdgcn_mfma_f32_16x16x32_bf16(af[m], bfr[n2], acc[m][n2], 0, 0, 0);
  }

  int rq = lane >> 4;
  #pragma unroll
  for (int m = 0; m < 4; ++m) {
    #pragma unroll
    for (int r = 0; r < 4; ++r) {
      int row = bm + wm + m * 16 + rq * 4 + r;
      if (row < M) {
        #pragma unroll
        for (int n2 = 0; n2 < 4; ++n2)
          C[(size_t)row * Nc + bn + wn + n2 * 16 + r16] = f2b(acc[m][n2][r]);
      }
    }
  }
}

// ---------- 4. attention logits from bf16 H ----------
template<int HH>
__global__ __launch_bounds__(128)
void logits_kernel(const unsigned short* __restrict__ H,
                   const float* __restrict__ a_s, const float* __restrict__ a_d,
                   float* __restrict__ al_s, float* __restrict__ al_d, int N)
{
  int n = blockIdx.x, t = threadIdx.x;
  int wv = t >> 6, lane = t & 63;
  __shared__ float tmp[2][2];
  #pragma unroll
  for (int h = 0; h < HH; ++h) {
    float hv = b2f(H[(size_t)n * HH * HC + h * HC + t]);
    float ps = hv * a_s[h * HC + t];
    float pd = hv * a_d[h * HC + t];
    #pragma unroll
    for (int off = 32; off; off >>= 1) { ps += __shfl_down(ps, off); pd += __shfl_down(pd, off); }
    if (lane == 0) { tmp[0][wv] = ps; tmp[1][wv] = pd; }
    __syncthreads();
    if (t == 0) {
      al_s[n * HH + h] = tmp[0][0] + tmp[0][1];
      al_d[n * HH + h] = tmp[1][0] + tmp[1][1];
    }
    __syncthreads();
  }
}

// ---------- 5. CSR build ----------
__global__ void zero_kernel(int* __restrict__ p, int n)
{
  int i = blockIdx.x * blockDim.x + threadIdx.x;
  if (i < n) p[i] = 0;
}

__global__ void count_kernel(const int* __restrict__ ei, int E, int N, int* __restrict__ deg)
{
  int e = blockIdx.x * blockDim.x + threadIdx.x;
  if (e < E + N) {
    int dst = (e < E) ? ei[E + e] : (e - E);
    atomicAdd(&deg[dst], 1);
  }
}

__global__ __launch_bounds__(1024)
void scan_kernel(const int* __restrict__ deg, int* __restrict__ rowptr,
                 int* __restrict__ fill, int N)
{
  __shared__ int sums[1024];
  int t = threadIdx.x;
  int CH = (N + 1023) >> 10;
  int base = t * CH;
  int s = 0;
  for (int i = 0; i < CH; ++i) if (base + i < N) s += deg[base + i];
  sums[t] = s;
  __syncthreads();
  for (int off = 1; off < 1024; off <<= 1) {
    int v = (t >= off) ? sums[t - off] : 0;
    __syncthreads();
    sums[t] += v;
    __syncthreads();
  }
  int run = sums[t] - s;  // exclusive prefix
  for (int i = 0; i < CH; ++i) {
    if (base + i < N) {
      rowptr[base + i] = run;
      fill[base + i]   = run;
      run += deg[base + i];
    }
  }
  if (t == 1023) rowptr[N] = run;
}

__global__ void scatter_kernel(const int* __restrict__ ei, int E, int N,
                               int* __restrict__ fill, int* __restrict__ csr_src)
{
  int e = blockIdx.x * blockDim.x + threadIdx.x;
  if (e < E + N) {
    int src, dst;
    if (e < E) { src = ei[e]; dst = ei[E + e]; }
    else       { src = dst = e - E; }
    int pos = atomicAdd(&fill[dst], 1);
    csr_src[pos] = src;
  }
}

// ---------- 6. per-dst softmax + aggregate + bias + ELU (bf16 H in, bf16 out) ----------
template<int HH>
__global__ __launch_bounds__(HH * 64)
void agg_kernel(const unsigned short* __restrict__ H,
                const float* __restrict__ al_s, const float* __restrict__ al_d,
                const int* __restrict__ rowptr, const int* __restrict__ csr_src,
                const float* __restrict__ bias, unsigned short* __restrict__ out, int N)
{
  int n = blockIdx.x;
  int h = threadIdx.x >> 6;
  int lane = threadIdx.x & 63;
  int rs = rowptr[n], re = rowptr[n + 1];
  float ald = al_d[n * HH + h];

  // online (max, sum) per lane
  float m = -1e30f, s = 0.f;
  for (int i = rs + lane; i < re; i += 64) {
    int src = csr_src[i];
    float e = leaky02(al_s[src * HH + h] + ald);
    float Mx = fmaxf(m, e);
    s = s * __expf(m - Mx) + __expf(e - Mx);
    m = Mx;
  }
  #pragma unroll
  for (int off = 32; off; off >>= 1) {
    float m2 = __shfl_down(m, off);
    float s2 = __shfl_down(s, off);
    float Mx = fmaxf(m, m2);
    s = s * __expf(m - Mx) + s2 * __expf(m2 - Mx);
    m = Mx;
  }
  m = __shfl(m, 0);
  s = __shfl(s, 0);
  float inv_den = 1.f / (s + 1e-16f);

  float acc0 = 0.f, acc1 = 0.f;
  for (int i = rs; i < re; ++i) {
    int src = csr_src[i];
    float e = leaky02(al_s[src * HH + h] + ald);
    float wgt = __expf(e - m) * inv_den;
    unsigned v = *(const unsigned*)&H[(size_t)src * HH * HC + h * HC + 2 * lane];
    acc0 += wgt * b2f((unsigned short)(v & 0xffffu));
    acc1 += wgt * b2f((unsigned short)(v >> 16));
  }
  float o0 = eluf(acc0 + bias[h * HC + 2 * lane]);
  float o1 = eluf(acc1 + bias[h * HC + 2 * lane + 1]);
  unsigned packed = (unsigned)f2b(o0) | ((unsigned)f2b(o1) << 16);
  *(unsigned*)&out[(size_t)n * HH * HC + h * HC + 2 * lane] = packed;
}

// ---------- 7. global max pool (bf16 in, fp32 out) ----------
static __device__ __forceinline__ unsigned enc_f(float f)
{
  unsigned u = __float_as_uint(f);
  return (u & 0x80000000u) ? ~u : (u | 0x80000000u);
}
static __device__ __forceinline__ float dec_f(unsigned u)
{
  return (u & 0x80000000u) ? __uint_as_float(u & 0x7fffffffu) : __uint_as_float(~u);
}

__global__ void pool_init_kernel(unsigned* __restrict__ p, int n)
{
  int i = blockIdx.x * blockDim.x + threadIdx.x;
  if (i < n) p[i] = 0x00800000u;  // enc(-FLT_MAX)
}

__global__ void pool_scatter_kernel(const unsigned short* __restrict__ x, const int* __restrict__ batch,
                                    unsigned* __restrict__ pool, int N)
{
  int i = blockIdx.x * blockDim.x + threadIdx.x;
  if (i < N * HC) {
    int n = i >> 7, c = i & (HC - 1);
    atomicMax(&pool[batch[n] * HC + c], enc_f(b2f(x[i])));
  }
}

__global__ void pool_final_kernel(const unsigned* __restrict__ pool, float* __restrict__ out, int n)
{
  int i = blockIdx.x * blockDim.x + threadIdx.x;
  if (i < n) out[i] = dec_f(pool[i]);
}

// ---------- launch ----------
extern "C" void kernel_launch(void* const* d_in, const int* in_sizes, int n_in,
                              void* d_out, int out_size, void* d_ws, size_t ws_size,
                              hipStream_t stream)
{
  const float* x_scalar = (const float*)d_in[0];
  const int* i0 = (const int*)d_in[1];
  const int* i1 = (const int*)d_in[2];
  const int* i2 = (const int*)d_in[3];
  const int* i3 = (const int*)d_in[4];
  const int* i4 = (const int*)d_in[5];
  const int* ei = (const int*)d_in[6];
  const int* batch = (const int*)d_in[7];
  const float* e0 = (const float*)d_in[8];
  const float* e1 = (const float*)d_in[9];
  const float* e2 = (const float*)d_in[10];
  const float* e3 = (const float*)d_in[11];
  const float* e4 = (const float*)d_in[12];
  const float* ln_g = (const float*)d_in[13];
  const float* ln_b = (const float*)d_in[14];
  const float* W1 = (const float*)d_in[15];
  const float* as1 = (const float*)d_in[16];
  const float* ad1 = (const float*)d_in[17];
  const float* b1 = (const float*)d_in[18];
  const float* W2 = (const float*)d_in[19];
  const float* as2 = (const float*)d_in[20];
  const float* ad2 = (const float*)d_in[21];
  const float* b2 = (const float*)d_in[22];

  const int N  = in_sizes[0] / SF;
  const int E  = in_sizes[6] / 2;
  const int Et = E + N;
  const int Bg = out_size / HC;
  const int MT = (N + 127) / 128;   // row tiles

  char* w = (char*)d_ws;
  auto alloc = [&](size_t bytes) -> char* {
    char* p = w;
    w += (bytes + 255) & ~(size_t)255;
    return p;
  };
  unsigned short* featsb = (unsigned short*)alloc((size_t)N * KP1 * 2);
  unsigned short* H1b    = (unsigned short*)alloc((size_t)N * 512 * 2);
  unsigned short* X2b    = (unsigned short*)alloc((size_t)N * 512 * 2);
  unsigned short* H2b    = (unsigned short*)alloc((size_t)N * HC * 2);
  unsigned short* X3b    = (unsigned short*)alloc((size_t)N * HC * 2);
  unsigned short* W1t    = (unsigned short*)alloc((size_t)512 * KP1 * 2);
  unsigned short* W2t    = (unsigned short*)alloc((size_t)HC * 512 * 2);
  float* als1    = (float*)alloc((size_t)N * 4 * 4);
  float* ald1    = (float*)alloc((size_t)N * 4 * 4);
  float* als2    = (float*)alloc((size_t)N * 4);
  float* ald2    = (float*)alloc((size_t)N * 4);
  int*   deg     = (int*)alloc((size_t)N * 4);
  int*   rowptr  = (int*)alloc((size_t)(N + 1) * 4);
  int*   fill    = (int*)alloc((size_t)N * 4);
  int*   csr_src = (int*)alloc((size_t)Et * 4);
  unsigned* pool = (unsigned*)alloc((size_t)Bg * HC * 4);

  // weight packing (constant per call) + features
  pack_wt_kernel<<<(512 * KP1 + 255) / 256, 256, 0, stream>>>(W1, W1t, DIN, 512, KP1);
  pack_wt_kernel<<<(HC * 512 + 255) / 256, 256, 0, stream>>>(W2, W2t, 512, HC, 512);
  feat_ln_kernel<<<N, 256, 0, stream>>>(x_scalar, i0, i1, i2, i3, i4,
                                        e0, e1, e2, e3, e4, ln_g, ln_b, featsb, N);

  // CSR build (independent of features)
  zero_kernel<<<(N + 255) / 256, 256, 0, stream>>>(deg, N);
  count_kernel<<<(Et + 255) / 256, 256, 0, stream>>>(ei, E, N, deg);
  scan_kernel<<<1, 1024, 0, stream>>>(deg, rowptr, fill, N);
  scatter_kernel<<<(Et + 255) / 256, 256, 0, stream>>>(ei, E, N, fill, csr_src);

  // layer 1
  gemm_bf16_kernel<KP1><<<dim3(512 / 128, MT), 256, 0, stream>>>(featsb, W1t, H1b, N, 512);
  logits_kernel<4><<<N, 128, 0, stream>>>(H1b, as1, ad1, als1, ald1, N);
  agg_kernel<4><<<N, 256, 0, stream>>>(H1b, als1, ald1, rowptr, csr_src, b1, X2b, N);

  // layer 2
  gemm_bf16_kernel<512><<<dim3(1, MT), 256, 0, stream>>>(X2b, W2t, H2b, N, HC);
  logits_kernel<1><<<N, 128, 0, stream>>>(H2b, as2, ad2, als2, ald2, N);
  agg_kernel<1><<<N, 64, 0, stream>>>(H2b, als2, ald2, rowptr, csr_src, b2, X3b, N);

  // pool
  pool_init_kernel<<<(Bg * HC + 255) / 256, 256, 0, stream>>>(pool, Bg * HC);
  pool_scatter_kernel<<<(N * HC + 255) / 256, 256, 0, stream>>>(X3b, batch, pool, N);
  pool_final_kernel<<<(Bg * HC + 255) / 256, 256, 0, stream>>>(pool, (float*)d_out, Bg * HC);
}

// Round 3
// 417.172 us; speedup vs baseline: 1.2137x; 1.0477x over previous
//
#include <hip/hip_runtime.h>
#include <math.h>

#define SF 16
#define ED 32
#define LTOK 20
#define DIN 176
#define KP1 192   // DIN padded to multiple of 32
#define HC 128

typedef _Float16 f16x8 __attribute__((ext_vector_type(8)));
typedef float f32x4 __attribute__((ext_vector_type(4)));

static __device__ __forceinline__ float leaky02(float x) { return x >= 0.f ? x : 0.2f * x; }
static __device__ __forceinline__ float eluf(float x)    { return x > 0.f ? x : expm1f(x); }
static __device__ __forceinline__ unsigned short f2h(float f)
{
  _Float16 h = (_Float16)f;
  return __builtin_bit_cast(unsigned short, h);
}
static __device__ __forceinline__ float h2f(unsigned short u)
{
  return (float)__builtin_bit_cast(_Float16, u);
}

// ---------- 0a. pack W [K][Nc] fp32 -> Wt [Nc][KPad] f16 (zero pad) ----------
__global__ void pack_wt_kernel(const float* __restrict__ W, unsigned short* __restrict__ Wt,
                               int K, int Nc, int KPad)
{
  int i = blockIdx.x * blockDim.x + threadIdx.x;
  if (i < Nc * KPad) {
    int n = i / KPad;
    int k = i - n * KPad;
    float v = (k < K) ? W[(size_t)k * Nc + n] : 0.f;
    Wt[i] = f2h(v);
  }
}

// ---------- 0b. v_s[k][h] = sum_c W1[k][h*128+c]*a_s[h][c] (and v_d) ----------
__global__ __launch_bounds__(256)
void prep_attn_kernel(const float* __restrict__ W1, const float* __restrict__ as1,
                      const float* __restrict__ ad1,
                      float* __restrict__ vs, float* __restrict__ vd)
{
  int k = blockIdx.x;                 // 0..175
  int h = threadIdx.x >> 6, lane = threadIdx.x & 63;
  const float* row = W1 + (size_t)k * 512 + h * HC;
  float s = row[lane] * as1[h * HC + lane] + row[lane + 64] * as1[h * HC + lane + 64];
  float d = row[lane] * ad1[h * HC + lane] + row[lane + 64] * ad1[h * HC + lane + 64];
  #pragma unroll
  for (int off = 32; off; off >>= 1) { s += __shfl_down(s, off); d += __shfl_down(d, off); }
  if (lane == 0) { vs[k * 4 + h] = s; vd[k * 4 + h] = d; }
}

// ---------- 1. features + LayerNorm -> f16 [N][KP1], fused attention logits ----------
__global__ __launch_bounds__(256)
void feat_ln_kernel(const float* __restrict__ xs,
                    const int* __restrict__ i0, const int* __restrict__ i1,
                    const int* __restrict__ i2, const int* __restrict__ i3,
                    const int* __restrict__ i4,
                    const float* __restrict__ e0, const float* __restrict__ e1,
                    const float* __restrict__ e2, const float* __restrict__ e3,
                    const float* __restrict__ e4,
                    const float* __restrict__ g, const float* __restrict__ b,
                    const float4* __restrict__ vs, const float4* __restrict__ vd,
                    unsigned short* __restrict__ out,
                    float* __restrict__ als, float* __restrict__ ald, int N)
{
  int n = blockIdx.x;
  int t = threadIdx.x;
  __shared__ int toks[5 * LTOK];
  __shared__ float red[2][4];
  __shared__ float redl[8][4];
  if (t < 5 * LTOK) {
    int f = t / LTOK, j = t - f * LTOK;
    const int* ip = (f == 0) ? i0 : (f == 1) ? i1 : (f == 2) ? i2 : (f == 3) ? i3 : i4;
    toks[t] = ip[n * LTOK + j];
  }
  __syncthreads();
  float v = 0.f;
  if (t < SF) {
    v = xs[n * SF + t];
  } else if (t < DIN) {
    int f = (t - SF) >> 5;
    int c = (t - SF) & 31;
    const float* ep = (f == 0) ? e0 : (f == 1) ? e1 : (f == 2) ? e2 : (f == 3) ? e3 : e4;
    float sum = 0.f, cnt = 0.f;
    #pragma unroll
    for (int j = 0; j < LTOK; ++j) {
      int idx = toks[f * LTOK + j];
      if (idx != 0) { sum += ep[idx * ED + c]; cnt += 1.f; }
    }
    v = sum / (cnt + 1e-9f);
  }
  float p  = (t < DIN) ? v : 0.f;
  float p2 = p * p;
  #pragma unroll
  for (int off = 32; off; off >>= 1) { p += __shfl_down(p, off); p2 += __shfl_down(p2, off); }
  int wv = t >> 6, lane = t & 63;
  if (lane == 0) { red[0][wv] = p; red[1][wv] = p2; }
  __syncthreads();
  float tot  = red[0][0] + red[0][1] + red[0][2] + red[0][3];
  float tot2 = red[1][0] + red[1][1] + red[1][2] + red[1][3];
  float mu   = tot * (1.f / DIN);
  float var  = fmaxf(tot2 * (1.f / DIN) - mu * mu, 0.f);
  float rstd = rsqrtf(var + 1e-5f);

  float y = 0.f;
  float4 vsv = make_float4(0.f, 0.f, 0.f, 0.f), vdv = vsv;
  if (t < DIN) {
    y = (v - mu) * rstd * g[t] + b[t];
    out[n * KP1 + t] = f2h(y);
    vsv = vs[t];
    vdv = vd[t];
  } else if (t < KP1) {
    out[n * KP1 + t] = 0;
  }
  float pr[8] = { y * vsv.x, y * vsv.y, y * vsv.z, y * vsv.w,
                  y * vdv.x, y * vdv.y, y * vdv.z, y * vdv.w };
  #pragma unroll
  for (int j = 0; j < 8; ++j)
    #pragma unroll
    for (int off = 32; off; off >>= 1) pr[j] += __shfl_down(pr[j], off);
  if (lane == 0)
    #pragma unroll
    for (int j = 0; j < 8; ++j) redl[j][wv] = pr[j];
  __syncthreads();
  if (t < 8) {
    float s = redl[t][0] + redl[t][1] + redl[t][2] + redl[t][3];
    if (t < 4) als[n * 4 + t] = s;
    else       ald[n * 4 + t - 4] = s;
  }
}

// ---------- 2. CSR build ----------
__global__ void zero_kernel(int* __restrict__ p, int n)
{
  int i = blockIdx.x * blockDim.x + threadIdx.x;
  if (i < n) p[i] = 0;
}

__global__ void count_kernel(const int* __restrict__ ei, int E, int N, int* __restrict__ deg)
{
  int e = blockIdx.x * blockDim.x + threadIdx.x;
  if (e < E + N) {
    int dst = (e < E) ? ei[E + e] : (e - E);
    atomicAdd(&deg[dst], 1);
  }
}

__global__ __launch_bounds__(1024)
void scan_kernel(const int* __restrict__ deg, int* __restrict__ rowptr,
                 int* __restrict__ fill, int N)
{
  __shared__ int sums[1024];
  int t = threadIdx.x;
  int CH = (N + 1023) >> 10;
  int base = t * CH;
  int s = 0;
  for (int i = 0; i < CH; ++i) if (base + i < N) s += deg[base + i];
  sums[t] = s;
  __syncthreads();
  for (int off = 1; off < 1024; off <<= 1) {
    int v = (t >= off) ? sums[t - off] : 0;
    __syncthreads();
    sums[t] += v;
    __syncthreads();
  }
  int run = sums[t] - s;  // exclusive prefix
  for (int i = 0; i < CH; ++i) {
    if (base + i < N) {
      rowptr[base + i] = run;
      fill[base + i]   = run;
      run += deg[base + i];
    }
  }
  if (t == 1023) rowptr[N] = run;
}

__global__ void scatter_kernel(const int* __restrict__ ei, int E, int N,
                               int* __restrict__ fill, int* __restrict__ csr_src)
{
  int e = blockIdx.x * blockDim.x + threadIdx.x;
  if (e < E + N) {
    int src, dst;
    if (e < E) { src = ei[e]; dst = ei[E + e]; }
    else       { src = dst = e - E; }
    int pos = atomicAdd(&fill[dst], 1);
    csr_src[pos] = src;
  }
}

// ---------- 3. layer-1 aggregation over FEATURES (one wave per dst, 4 heads share gather) ----------
__global__ __launch_bounds__(64)
void agg_feat_kernel(const unsigned short* __restrict__ F,   // [N][KP1] f16
                     const float4* __restrict__ als, const float4* __restrict__ ald,
                     const int* __restrict__ rowptr, const int* __restrict__ csr_src,
                     unsigned short* __restrict__ G, int N)  // [4][N][KP1] f16
{
  int n = blockIdx.x, lane = threadIdx.x;
  int rs = rowptr[n], re = rowptr[n + 1];
  float4 ad4 = ald[n];
  float aldv[4] = { ad4.x, ad4.y, ad4.z, ad4.w };

  float m[4], s[4];
  #pragma unroll
  for (int h = 0; h < 4; ++h) { m[h] = -1e30f; s[h] = 0.f; }
  for (int i = rs + lane; i < re; i += 64) {
    int src = csr_src[i];
    float4 a4 = als[src];
    float av[4] = { a4.x, a4.y, a4.z, a4.w };
    #pragma unroll
    for (int h = 0; h < 4; ++h) {
      float e = leaky02(av[h] + aldv[h]);
      float Mx = fmaxf(m[h], e);
      s[h] = s[h] * __expf(m[h] - Mx) + __expf(e - Mx);
      m[h] = Mx;
    }
  }
  #pragma unroll
  for (int off = 32; off; off >>= 1) {
    #pragma unroll
    for (int h = 0; h < 4; ++h) {
      float m2 = __shfl_down(m[h], off);
      float s2 = __shfl_down(s[h], off);
      float Mx = fmaxf(m[h], m2);
      s[h] = s[h] * __expf(m[h] - Mx) + s2 * __expf(m2 - Mx);
      m[h] = Mx;
    }
  }
  float inv[4];
  #pragma unroll
  for (int h = 0; h < 4; ++h) {
    m[h] = __shfl(m[h], 0);
    float sh = __shfl(s[h], 0);
    inv[h] = 1.f / (sh + 1e-16f);
  }

  float acc[4][4] = {};
  int k4 = lane * 4;
  bool active = lane < 44;                 // 44*4 = 176 real channels
  const unsigned short* Fb = F + k4;
  for (int i = rs; i < re; ++i) {
    int src = csr_src[i];
    float4 a4 = als[src];
    float av[4] = { a4.x, a4.y, a4.z, a4.w };
    float w[4];
    #pragma unroll
    for (int h = 0; h < 4; ++h)
      w[h] = __expf(leaky02(av[h] + aldv[h]) - m[h]) * inv[h];
    if (active) {
      ushort4 vv = *(const ushort4*)(Fb + (size_t)src * KP1);
      float f0 = h2f(vv.x), f1 = h2f(vv.y), f2v = h2f(vv.z), f3 = h2f(vv.w);
      #pragma unroll
      for (int h = 0; h < 4; ++h) {
        acc[h][0] += w[h] * f0;  acc[h][1] += w[h] * f1;
        acc[h][2] += w[h] * f2v; acc[h][3] += w[h] * f3;
      }
    }
  }
  if (lane < 48) {                         // also writes zero tail [176,192)
    #pragma unroll
    for (int h = 0; h < 4; ++h) {
      ushort4 o;
      o.x = f2h(acc[h][0]); o.y = f2h(acc[h][1]);
      o.z = f2h(acc[h][2]); o.w = f2h(acc[h][3]);
      *(ushort4*)&G[((size_t)h * N + n) * KP1 + k4] = o;
    }
  }
}

// ---------- 4. MFMA f16 GEMM: C[:, zcols] = A_z[M,KPad] @ Bt_z[128,KPad]^T (+bias, ELU) ----------
template<int KPad>
__global__ __launch_bounds__(256)
void gemm_f16_kernel(const unsigned short* __restrict__ A, const unsigned short* __restrict__ Bt,
                     unsigned short* __restrict__ C, int M, int Nc,
                     size_t aStrideZ, size_t bStrideZ, int cColStrideZ,
                     const float* __restrict__ bias, int act)
{
  A  += blockIdx.z * aStrideZ;
  Bt += blockIdx.z * bStrideZ;
  int colZ = blockIdx.z * cColStrideZ;

  __shared__ __align__(16) unsigned short As[4][128][8];
  __shared__ __align__(16) unsigned short Bs[4][128][8];
  int tid  = threadIdx.x;
  int lane = tid & 63, wave = tid >> 6;
  int wm = (wave >> 1) << 6, wn = (wave & 1) << 6;
  int bm = blockIdx.y << 7, bn = blockIdx.x << 7;

  int srow = tid >> 1;
  int skc  = (tid & 1) << 1;
  const unsigned short* Arow = A  + (size_t)(bm + srow) * KPad + skc * 8;
  const unsigned short* Brow = Bt + (size_t)(bn + srow) * KPad + skc * 8;
  bool aok = (bm + srow) < M;

  f32x4 acc[4][4];
  #pragma unroll
  for (int m = 0; m < 4; ++m)
    #pragma unroll
    for (int n2 = 0; n2 < 4; ++n2) acc[m][n2] = (f32x4){0.f, 0.f, 0.f, 0.f};

  int kc  = lane >> 4;
  int r16 = lane & 15;

  for (int k0 = 0; k0 < KPad; k0 += 32) {
    int4 av0 = make_int4(0, 0, 0, 0), av1 = make_int4(0, 0, 0, 0);
    if (aok) {
      av0 = *(const int4*)(Arow + k0);
      av1 = *(const int4*)(Arow + k0 + 8);
    }
    int4 bv0 = *(const int4*)(Brow + k0);
    int4 bv1 = *(const int4*)(Brow + k0 + 8);
    __syncthreads();
    *(int4*)&As[skc][srow][0]     = av0;
    *(int4*)&As[skc + 1][srow][0] = av1;
    *(int4*)&Bs[skc][srow][0]     = bv0;
    *(int4*)&Bs[skc + 1][srow][0] = bv1;
    __syncthreads();

    f16x8 af[4], bfr[4];
    #pragma unroll
    for (int m = 0; m < 4; ++m)  af[m]  = *(const f16x8*)&As[kc][wm + m * 16 + r16][0];
    #pragma unroll
    for (int n2 = 0; n2 < 4; ++n2) bfr[n2] = *(const f16x8*)&Bs[kc][wn + n2 * 16 + r16][0];
    #pragma unroll
    for (int m = 0; m < 4; ++m)
      #pragma unroll
      for (int n2 = 0; n2 < 4; ++n2)
        acc[m][n2] = __builtin_amdgcn_mfma_f32_16x16x32_f16(af[m], bfr[n2], acc[m][n2], 0, 0, 0);
  }

  int rq = lane >> 4;
  #pragma unroll
  for (int m = 0; m < 4; ++m) {
    #pragma unroll
    for (int r = 0; r < 4; ++r) {
      int row = bm + wm + m * 16 + rq * 4 + r;
      if (row < M) {
        #pragma unroll
        for (int n2 = 0; n2 < 4; ++n2) {
          int col = colZ + bn + wn + n2 * 16 + r16;
          float val = acc[m][n2][r];
          if (bias) val += bias[col];
          if (act)  val = eluf(val);
          C[(size_t)row * Nc + col] = f2h(val);
        }
      }
    }
  }
}

// ---------- 5. layer-2 attention logits from f16 H2 ----------
__global__ __launch_bounds__(128)
void logits2_kernel(const unsigned short* __restrict__ H,
                    const float* __restrict__ a_s, const float* __restrict__ a_d,
                    float* __restrict__ al_s, float* __restrict__ al_d, int N)
{
  int n = blockIdx.x, t = threadIdx.x;
  int wv = t >> 6, lane = t & 63;
  __shared__ float tmp[2][2];
  float hv = h2f(H[(size_t)n * HC + t]);
  float ps = hv * a_s[t];
  float pd = hv * a_d[t];
  #pragma unroll
  for (int off = 32; off; off >>= 1) { ps += __shfl_down(ps, off); pd += __shfl_down(pd, off); }
  if (lane == 0) { tmp[0][wv] = ps; tmp[1][wv] = pd; }
  __syncthreads();
  if (t == 0) {
    al_s[n] = tmp[0][0] + tmp[0][1];
    al_d[n] = tmp[1][0] + tmp[1][1];
  }
}

// ---------- 6. layer-2 aggregation (H2 gather) + bias + ELU ----------
__global__ __launch_bounds__(64)
void agg_h2_kernel(const unsigned short* __restrict__ H,
                   const float* __restrict__ al_s, const float* __restrict__ al_d,
                   const int* __restrict__ rowptr, const int* __restrict__ csr_src,
                   const float* __restrict__ bias, unsigned short* __restrict__ out, int N)
{
  int n = blockIdx.x;
  int lane = threadIdx.x;
  int rs = rowptr[n], re = rowptr[n + 1];
  float ald = al_d[n];

  float m = -1e30f, s = 0.f;
  for (int i = rs + lane; i < re; i += 64) {
    int src = csr_src[i];
    float e = leaky02(al_s[src] + ald);
    float Mx = fmaxf(m, e);
    s = s * __expf(m - Mx) + __expf(e - Mx);
    m = Mx;
  }
  #pragma unroll
  for (int off = 32; off; off >>= 1) {
    float m2 = __shfl_down(m, off);
    float s2 = __shfl_down(s, off);
    float Mx = fmaxf(m, m2);
    s = s * __expf(m - Mx) + s2 * __expf(m2 - Mx);
    m = Mx;
  }
  m = __shfl(m, 0);
  s = __shfl(s, 0);
  float inv_den = 1.f / (s + 1e-16f);

  float acc0 = 0.f, acc1 = 0.f;
  for (int i = rs; i < re; ++i) {
    int src = csr_src[i];
    float e = leaky02(al_s[src] + ald);
    float wgt = __expf(e - m) * inv_den;
    ushort2 v = *(const ushort2*)&H[(size_t)src * HC + 2 * lane];
    acc0 += wgt * h2f(v.x);
    acc1 += wgt * h2f(v.y);
  }
  float o0 = eluf(acc0 + bias[2 * lane]);
  float o1 = eluf(acc1 + bias[2 * lane + 1]);
  ushort2 o; o.x = f2h(o0); o.y = f2h(o1);
  *(ushort2*)&out[(size_t)n * HC + 2 * lane] = o;
}

// ---------- 7. global max pool ----------
static __device__ __forceinline__ unsigned enc_f(float f)
{
  unsigned u = __float_as_uint(f);
  return (u & 0x80000000u) ? ~u : (u | 0x80000000u);
}
static __device__ __forceinline__ float dec_f(unsigned u)
{
  return (u & 0x80000000u) ? __uint_as_float(u & 0x7fffffffu) : __uint_as_float(~u);
}

__global__ void pool_init_kernel(unsigned* __restrict__ p, int n)
{
  int i = blockIdx.x * blockDim.x + threadIdx.x;
  if (i < n) p[i] = 0x00800000u;  // enc(-FLT_MAX)
}

__global__ void pool_scatter_kernel(const unsigned short* __restrict__ x, const int* __restrict__ batch,
                                    unsigned* __restrict__ pool, int N)
{
  int i = blockIdx.x * blockDim.x + threadIdx.x;
  if (i < N * HC) {
    int n = i >> 7, c = i & (HC - 1);
    atomicMax(&pool[batch[n] * HC + c], enc_f(h2f(x[i])));
  }
}

__global__ void pool_final_kernel(const unsigned* __restrict__ pool, float* __restrict__ out, int n)
{
  int i = blockIdx.x * blockDim.x + threadIdx.x;
  if (i < n) out[i] = dec_f(pool[i]);
}

// ---------- launch ----------
extern "C" void kernel_launch(void* const* d_in, const int* in_sizes, int n_in,
                              void* d_out, int out_size, void* d_ws, size_t ws_size,
                              hipStream_t stream)
{
  const float* x_scalar = (const float*)d_in[0];
  const int* i0 = (const int*)d_in[1];
  const int* i1 = (const int*)d_in[2];
  const int* i2 = (const int*)d_in[3];
  const int* i3 = (const int*)d_in[4];
  const int* i4 = (const int*)d_in[5];
  const int* ei = (const int*)d_in[6];
  const int* batch = (const int*)d_in[7];
  const float* e0 = (const float*)d_in[8];
  const float* e1 = (const float*)d_in[9];
  const float* e2 = (const float*)d_in[10];
  const float* e3 = (const float*)d_in[11];
  const float* e4 = (const float*)d_in[12];
  const float* ln_g = (const float*)d_in[13];
  const float* ln_b = (const float*)d_in[14];
  const float* W1 = (const float*)d_in[15];
  const float* as1 = (const float*)d_in[16];
  const float* ad1 = (const float*)d_in[17];
  const float* b1 = (const float*)d_in[18];
  const float* W2 = (const float*)d_in[19];
  const float* as2 = (const float*)d_in[20];
  const float* ad2 = (const float*)d_in[21];
  const float* b2 = (const float*)d_in[22];

  const int N  = in_sizes[0] / SF;
  const int E  = in_sizes[6] / 2;
  const int Et = E + N;
  const int Bg = out_size / HC;
  const int MT = (N + 127) / 128;

  char* w = (char*)d_ws;
  auto alloc = [&](size_t bytes) -> char* {
    char* p = w;
    w += (bytes + 255) & ~(size_t)255;
    return p;
  };
  unsigned short* featsb = (unsigned short*)alloc((size_t)N * KP1 * 2);
  unsigned short* G      = (unsigned short*)alloc((size_t)4 * N * KP1 * 2);
  unsigned short* X2b    = (unsigned short*)alloc((size_t)N * 512 * 2);
  unsigned short* H2b    = (unsigned short*)alloc((size_t)N * HC * 2);
  unsigned short* X3b    = (unsigned short*)alloc((size_t)N * HC * 2);
  unsigned short* W1t    = (unsigned short*)alloc((size_t)512 * KP1 * 2);
  unsigned short* W2t    = (unsigned short*)alloc((size_t)HC * 512 * 2);
  float* vs      = (float*)alloc((size_t)KP1 * 4 * 4);
  float* vd      = (float*)alloc((size_t)KP1 * 4 * 4);
  float* als1    = (float*)alloc((size_t)N * 4 * 4);
  float* ald1    = (float*)alloc((size_t)N * 4 * 4);
  float* als2    = (float*)alloc((size_t)N * 4);
  float* ald2    = (float*)alloc((size_t)N * 4);
  int*   deg     = (int*)alloc((size_t)N * 4);
  int*   rowptr  = (int*)alloc((size_t)(N + 1) * 4);
  int*   fill    = (int*)alloc((size_t)N * 4);
  int*   csr_src = (int*)alloc((size_t)Et * 4);
  unsigned* pool = (unsigned*)alloc((size_t)Bg * HC * 4);

  // constants per call
  pack_wt_kernel<<<(512 * KP1 + 255) / 256, 256, 0, stream>>>(W1, W1t, DIN, 512, KP1);
  pack_wt_kernel<<<(HC * 512 + 255) / 256, 256, 0, stream>>>(W2, W2t, 512, HC, 512);
  prep_attn_kernel<<<DIN, 256, 0, stream>>>(W1, as1, ad1, vs, vd);

  // features + LN + fused layer-1 logits
  feat_ln_kernel<<<N, 256, 0, stream>>>(x_scalar, i0, i1, i2, i3, i4,
                                        e0, e1, e2, e3, e4, ln_g, ln_b,
                                        (const float4*)vs, (const float4*)vd,
                                        featsb, als1, ald1, N);

  // CSR
  zero_kernel<<<(N + 255) / 256, 256, 0, stream>>>(deg, N);
  count_kernel<<<(Et + 255) / 256, 256, 0, stream>>>(ei, E, N, deg);
  scan_kernel<<<1, 1024, 0, stream>>>(deg, rowptr, fill, N);
  scatter_kernel<<<(Et + 255) / 256, 256, 0, stream>>>(ei, E, N, fill, csr_src);

  // layer 1: aggregate feats (4 heads share gather), then per-head GEMM (+b1, ELU)
  agg_feat_kernel<<<N, 64, 0, stream>>>(featsb, (const float4*)als1, (const float4*)ald1,
                                        rowptr, csr_src, G, N);
  gemm_f16_kernel<KP1><<<dim3(1, MT, 4), 256, 0, stream>>>(
      G, W1t, X2b, N, 512, (size_t)N * KP1, (size_t)HC * KP1, HC, b1, 1);

  // layer 2: GEMM (raw H2), logits, aggregate (+b2, ELU)
  gemm_f16_kernel<512><<<dim3(1, MT, 1), 256, 0, stream>>>(
      X2b, W2t, H2b, N, HC, 0, 0, 0, nullptr, 0);
  logits2_kernel<<<N, 128, 0, stream>>>(H2b, as2, ad2, als2, ald2, N);
  agg_h2_kernel<<<N, 64, 0, stream>>>(H2b, als2, ald2, rowptr, csr_src, b2, X3b, N);

  // pool
  pool_init_kernel<<<(Bg * HC + 255) / 256, 256, 0, stream>>>(pool, Bg * HC);
  pool_scatter_kernel<<<(N * HC + 255) / 256, 256, 0, stream>>>(X3b, batch, pool, N);
  pool_final_kernel<<<(Bg * HC + 255) / 256, 256, 0, stream>>>(pool, (float*)d_out, Bg * HC);
}

// Round 4
// 317.648 us; speedup vs baseline: 1.5939x; 1.3133x over previous
//
#include <hip/hip_runtime.h>
#include <math.h>

#define SF 16
#define ED 32
#define LTOK 20
#define DIN 176
#define KP1 192   // DIN padded to multiple of 32
#define HC 128

typedef _Float16 f16x8 __attribute__((ext_vector_type(8)));
typedef float f32x4 __attribute__((ext_vector_type(4)));

static __device__ __forceinline__ float leaky02(float x) { return x >= 0.f ? x : 0.2f * x; }
static __device__ __forceinline__ float eluf(float x)    { return x > 0.f ? x : expm1f(x); }
static __device__ __forceinline__ unsigned short f2h(float f)
{
  _Float16 h = (_Float16)f;
  return __builtin_bit_cast(unsigned short, h);
}
static __device__ __forceinline__ float h2f(unsigned short u)
{
  return (float)__builtin_bit_cast(_Float16, u);
}

// ---------- 0a. pack W [K][Nc] fp32 -> Wt [Nc][KPad] f16 (zero pad) ----------
__global__ void pack_wt_kernel(const float* __restrict__ W, unsigned short* __restrict__ Wt,
                               int K, int Nc, int KPad)
{
  int i = blockIdx.x * blockDim.x + threadIdx.x;
  if (i < Nc * KPad) {
    int n = i / KPad;
    int k = i - n * KPad;
    float v = (k < K) ? W[(size_t)k * Nc + n] : 0.f;
    Wt[i] = f2h(v);
  }
}

// ---------- 0b. v_s[k][h] = sum_c W1[k][h*128+c]*a_s[h][c] (and v_d) ----------
__global__ __launch_bounds__(256)
void prep_attn_kernel(const float* __restrict__ W1, const float* __restrict__ as1,
                      const float* __restrict__ ad1,
                      float* __restrict__ vs, float* __restrict__ vd)
{
  int k = blockIdx.x;                 // 0..175
  int h = threadIdx.x >> 6, lane = threadIdx.x & 63;
  const float* row = W1 + (size_t)k * 512 + h * HC;
  float s = row[lane] * as1[h * HC + lane] + row[lane + 64] * as1[h * HC + lane + 64];
  float d = row[lane] * ad1[h * HC + lane] + row[lane + 64] * ad1[h * HC + lane + 64];
  #pragma unroll
  for (int off = 32; off; off >>= 1) { s += __shfl_down(s, off); d += __shfl_down(d, off); }
  if (lane == 0) { vs[k * 4 + h] = s; vd[k * 4 + h] = d; }
}

// ---------- 1. features + LayerNorm -> f16 [N][KP1], fused attention logits ----------
__global__ __launch_bounds__(256)
void feat_ln_kernel(const float* __restrict__ xs,
                    const int* __restrict__ i0, const int* __restrict__ i1,
                    const int* __restrict__ i2, const int* __restrict__ i3,
                    const int* __restrict__ i4,
                    const float* __restrict__ e0, const float* __restrict__ e1,
                    const float* __restrict__ e2, const float* __restrict__ e3,
                    const float* __restrict__ e4,
                    const float* __restrict__ g, const float* __restrict__ b,
                    const float4* __restrict__ vs, const float4* __restrict__ vd,
                    unsigned short* __restrict__ out,
                    float* __restrict__ als, float* __restrict__ ald, int N)
{
  int n = blockIdx.x;
  int t = threadIdx.x;
  __shared__ int toks[5 * LTOK];
  __shared__ float red[2][4];
  __shared__ float redl[8][4];
  if (t < 5 * LTOK) {
    int f = t / LTOK, j = t - f * LTOK;
    const int* ip = (f == 0) ? i0 : (f == 1) ? i1 : (f == 2) ? i2 : (f == 3) ? i3 : i4;
    toks[t] = ip[n * LTOK + j];
  }
  __syncthreads();
  float v = 0.f;
  if (t < SF) {
    v = xs[n * SF + t];
  } else if (t < DIN) {
    int f = (t - SF) >> 5;
    int c = (t - SF) & 31;
    const float* ep = (f == 0) ? e0 : (f == 1) ? e1 : (f == 2) ? e2 : (f == 3) ? e3 : e4;
    // Row 0 is a valid padding row: load ALL tokens unconditionally so the
    // 20 gathers are independent and stay in flight, then mask-accumulate.
    float vals[LTOK];
    #pragma unroll
    for (int j = 0; j < LTOK; ++j) {
      int idx = toks[f * LTOK + j];
      vals[j] = ep[idx * ED + c];
    }
    float sum = 0.f, cnt = 0.f;
    #pragma unroll
    for (int j = 0; j < LTOK; ++j) {
      int idx = toks[f * LTOK + j];
      if (idx != 0) { sum += vals[j]; cnt += 1.f; }
    }
    v = sum / (cnt + 1e-9f);
  }
  float p  = (t < DIN) ? v : 0.f;
  float p2 = p * p;
  #pragma unroll
  for (int off = 32; off; off >>= 1) { p += __shfl_down(p, off); p2 += __shfl_down(p2, off); }
  int wv = t >> 6, lane = t & 63;
  if (lane == 0) { red[0][wv] = p; red[1][wv] = p2; }
  __syncthreads();
  float tot  = red[0][0] + red[0][1] + red[0][2] + red[0][3];
  float tot2 = red[1][0] + red[1][1] + red[1][2] + red[1][3];
  float mu   = tot * (1.f / DIN);
  float var  = fmaxf(tot2 * (1.f / DIN) - mu * mu, 0.f);
  float rstd = rsqrtf(var + 1e-5f);

  float y = 0.f;
  float4 vsv = make_float4(0.f, 0.f, 0.f, 0.f), vdv = vsv;
  if (t < DIN) {
    y = (v - mu) * rstd * g[t] + b[t];
    out[n * KP1 + t] = f2h(y);
    vsv = vs[t];
    vdv = vd[t];
  } else if (t < KP1) {
    out[n * KP1 + t] = 0;
  }
  float pr[8] = { y * vsv.x, y * vsv.y, y * vsv.z, y * vsv.w,
                  y * vdv.x, y * vdv.y, y * vdv.z, y * vdv.w };
  #pragma unroll
  for (int j = 0; j < 8; ++j)
    #pragma unroll
    for (int off = 32; off; off >>= 1) pr[j] += __shfl_down(pr[j], off);
  if (lane == 0)
    #pragma unroll
    for (int j = 0; j < 8; ++j) redl[j][wv] = pr[j];
  __syncthreads();
  if (t < 8) {
    float s = redl[t][0] + redl[t][1] + redl[t][2] + redl[t][3];
    if (t < 4) als[n * 4 + t] = s;
    else       ald[n * 4 + t - 4] = s;
  }
}

// ---------- 2. CSR build ----------
__global__ void zero_kernel(int* __restrict__ p, int n)
{
  int i = blockIdx.x * blockDim.x + threadIdx.x;
  if (i < n) p[i] = 0;
}

__global__ void count_kernel(const int* __restrict__ ei, int E, int N, int* __restrict__ deg)
{
  int e = blockIdx.x * blockDim.x + threadIdx.x;
  if (e < E + N) {
    int dst = (e < E) ? ei[E + e] : (e - E);
    atomicAdd(&deg[dst], 1);
  }
}

__global__ __launch_bounds__(1024)
void scan_kernel(const int* __restrict__ deg, int* __restrict__ rowptr,
                 int* __restrict__ fill, int N)
{
  __shared__ int sums[1024];
  int t = threadIdx.x;
  int CH = (N + 1023) >> 10;
  int base = t * CH;
  int s = 0;
  for (int i = 0; i < CH; ++i) if (base + i < N) s += deg[base + i];
  sums[t] = s;
  __syncthreads();
  for (int off = 1; off < 1024; off <<= 1) {
    int v = (t >= off) ? sums[t - off] : 0;
    __syncthreads();
    sums[t] += v;
    __syncthreads();
  }
  int run = sums[t] - s;  // exclusive prefix
  for (int i = 0; i < CH; ++i) {
    if (base + i < N) {
      rowptr[base + i] = run;
      fill[base + i]   = run;
      run += deg[base + i];
    }
  }
  if (t == 1023) rowptr[N] = run;
}

__global__ void scatter_kernel(const int* __restrict__ ei, int E, int N,
                               int* __restrict__ fill, int* __restrict__ csr_src)
{
  int e = blockIdx.x * blockDim.x + threadIdx.x;
  if (e < E + N) {
    int src, dst;
    if (e < E) { src = ei[e]; dst = ei[E + e]; }
    else       { src = dst = e - E; }
    int pos = atomicAdd(&fill[dst], 1);
    csr_src[pos] = src;
  }
}

// ---------- 3. layer-1 aggregation over FEATURES (one wave per dst, 4 heads share gather) ----------
__global__ __launch_bounds__(64)
void agg_feat_kernel(const unsigned short* __restrict__ F,   // [N][KP1] f16
                     const float4* __restrict__ als, const float4* __restrict__ ald,
                     const int* __restrict__ rowptr, const int* __restrict__ csr_src,
                     unsigned short* __restrict__ G, int N)  // [4][N][KP1] f16
{
  int n = blockIdx.x, lane = threadIdx.x;
  int rs = rowptr[n], re = rowptr[n + 1];
  float4 ad4 = ald[n];
  float aldv[4] = { ad4.x, ad4.y, ad4.z, ad4.w };

  float m[4], s[4];
  #pragma unroll
  for (int h = 0; h < 4; ++h) { m[h] = -1e30f; s[h] = 0.f; }
  for (int i = rs + lane; i < re; i += 64) {
    int src = csr_src[i];
    float4 a4 = als[src];
    float av[4] = { a4.x, a4.y, a4.z, a4.w };
    #pragma unroll
    for (int h = 0; h < 4; ++h) {
      float e = leaky02(av[h] + aldv[h]);
      float Mx = fmaxf(m[h], e);
      s[h] = s[h] * __expf(m[h] - Mx) + __expf(e - Mx);
      m[h] = Mx;
    }
  }
  #pragma unroll
  for (int off = 32; off; off >>= 1) {
    #pragma unroll
    for (int h = 0; h < 4; ++h) {
      float m2 = __shfl_down(m[h], off);
      float s2 = __shfl_down(s[h], off);
      float Mx = fmaxf(m[h], m2);
      s[h] = s[h] * __expf(m[h] - Mx) + s2 * __expf(m2 - Mx);
      m[h] = Mx;
    }
  }
  float inv[4];
  #pragma unroll
  for (int h = 0; h < 4; ++h) {
    m[h] = __shfl(m[h], 0);
    float sh = __shfl(s[h], 0);
    inv[h] = 1.f / (sh + 1e-16f);
  }

  float acc[4][4] = {};
  int k4 = lane * 4;
  bool active = lane < 44;                 // 44*4 = 176 real channels
  const unsigned short* Fb = F + k4;
  for (int i = rs; i < re; ++i) {
    int src = csr_src[i];
    float4 a4 = als[src];
    float av[4] = { a4.x, a4.y, a4.z, a4.w };
    float w[4];
    #pragma unroll
    for (int h = 0; h < 4; ++h)
      w[h] = __expf(leaky02(av[h] + aldv[h]) - m[h]) * inv[h];
    if (active) {
      ushort4 vv = *(const ushort4*)(Fb + (size_t)src * KP1);
      float f0 = h2f(vv.x), f1 = h2f(vv.y), f2v = h2f(vv.z), f3 = h2f(vv.w);
      #pragma unroll
      for (int h = 0; h < 4; ++h) {
        acc[h][0] += w[h] * f0;  acc[h][1] += w[h] * f1;
        acc[h][2] += w[h] * f2v; acc[h][3] += w[h] * f3;
      }
    }
  }
  if (lane < 48) {                         // also writes zero tail [176,192)
    #pragma unroll
    for (int h = 0; h < 4; ++h) {
      ushort4 o;
      o.x = f2h(acc[h][0]); o.y = f2h(acc[h][1]);
      o.z = f2h(acc[h][2]); o.w = f2h(acc[h][3]);
      *(ushort4*)&G[((size_t)h * N + n) * KP1 + k4] = o;
    }
  }
}

// ---------- 4. MFMA f16 GEMM: C[:, zcols] = A_z[M,KPad] @ Bt_z[128,KPad]^T (+bias, ELU) ----------
template<int KPad>
__global__ __launch_bounds__(256)
void gemm_f16_kernel(const unsigned short* __restrict__ A, const unsigned short* __restrict__ Bt,
                     unsigned short* __restrict__ C, int M, int Nc,
                     size_t aStrideZ, size_t bStrideZ, int cColStrideZ,
                     const float* __restrict__ bias, int act)
{
  A  += blockIdx.z * aStrideZ;
  Bt += blockIdx.z * bStrideZ;
  int colZ = blockIdx.z * cColStrideZ;

  __shared__ __align__(16) unsigned short As[4][128][8];
  __shared__ __align__(16) unsigned short Bs[4][128][8];
  int tid  = threadIdx.x;
  int lane = tid & 63, wave = tid >> 6;
  int wm = (wave >> 1) << 6, wn = (wave & 1) << 6;
  int bm = blockIdx.y << 7, bn = blockIdx.x << 7;

  int srow = tid >> 1;
  int skc  = (tid & 1) << 1;
  const unsigned short* Arow = A  + (size_t)(bm + srow) * KPad + skc * 8;
  const unsigned short* Brow = Bt + (size_t)(bn + srow) * KPad + skc * 8;
  bool aok = (bm + srow) < M;

  f32x4 acc[4][4];
  #pragma unroll
  for (int m = 0; m < 4; ++m)
    #pragma unroll
    for (int n2 = 0; n2 < 4; ++n2) acc[m][n2] = (f32x4){0.f, 0.f, 0.f, 0.f};

  int kc  = lane >> 4;
  int r16 = lane & 15;

  for (int k0 = 0; k0 < KPad; k0 += 32) {
    int4 av0 = make_int4(0, 0, 0, 0), av1 = make_int4(0, 0, 0, 0);
    if (aok) {
      av0 = *(const int4*)(Arow + k0);
      av1 = *(const int4*)(Arow + k0 + 8);
    }
    int4 bv0 = *(const int4*)(Brow + k0);
    int4 bv1 = *(const int4*)(Brow + k0 + 8);
    __syncthreads();
    *(int4*)&As[skc][srow][0]     = av0;
    *(int4*)&As[skc + 1][srow][0] = av1;
    *(int4*)&Bs[skc][srow][0]     = bv0;
    *(int4*)&Bs[skc + 1][srow][0] = bv1;
    __syncthreads();

    f16x8 af[4], bfr[4];
    #pragma unroll
    for (int m = 0; m < 4; ++m)  af[m]  = *(const f16x8*)&As[kc][wm + m * 16 + r16][0];
    #pragma unroll
    for (int n2 = 0; n2 < 4; ++n2) bfr[n2] = *(const f16x8*)&Bs[kc][wn + n2 * 16 + r16][0];
    #pragma unroll
    for (int m = 0; m < 4; ++m)
      #pragma unroll
      for (int n2 = 0; n2 < 4; ++n2)
        acc[m][n2] = __builtin_amdgcn_mfma_f32_16x16x32_f16(af[m], bfr[n2], acc[m][n2], 0, 0, 0);
  }

  int rq = lane >> 4;
  #pragma unroll
  for (int m = 0; m < 4; ++m) {
    #pragma unroll
    for (int r = 0; r < 4; ++r) {
      int row = bm + wm + m * 16 + rq * 4 + r;
      if (row < M) {
        #pragma unroll
        for (int n2 = 0; n2 < 4; ++n2) {
          int col = colZ + bn + wn + n2 * 16 + r16;
          float val = acc[m][n2][r];
          if (bias) val += bias[col];
          if (act)  val = eluf(val);
          C[(size_t)row * Nc + col] = f2h(val);
        }
      }
    }
  }
}

// ---------- 5. layer-2 attention logits from f16 H2 ----------
__global__ __launch_bounds__(128)
void logits2_kernel(const unsigned short* __restrict__ H,
                    const float* __restrict__ a_s, const float* __restrict__ a_d,
                    float* __restrict__ al_s, float* __restrict__ al_d, int N)
{
  int n = blockIdx.x, t = threadIdx.x;
  int wv = t >> 6, lane = t & 63;
  __shared__ float tmp[2][2];
  float hv = h2f(H[(size_t)n * HC + t]);
  float ps = hv * a_s[t];
  float pd = hv * a_d[t];
  #pragma unroll
  for (int off = 32; off; off >>= 1) { ps += __shfl_down(ps, off); pd += __shfl_down(pd, off); }
  if (lane == 0) { tmp[0][wv] = ps; tmp[1][wv] = pd; }
  __syncthreads();
  if (t == 0) {
    al_s[n] = tmp[0][0] + tmp[0][1];
    al_d[n] = tmp[1][0] + tmp[1][1];
  }
}

// ---------- 6. layer-2 aggregation (H2 gather) + bias + ELU ----------
__global__ __launch_bounds__(64)
void agg_h2_kernel(const unsigned short* __restrict__ H,
                   const float* __restrict__ al_s, const float* __restrict__ al_d,
                   const int* __restrict__ rowptr, const int* __restrict__ csr_src,
                   const float* __restrict__ bias, unsigned short* __restrict__ out, int N)
{
  int n = blockIdx.x;
  int lane = threadIdx.x;
  int rs = rowptr[n], re = rowptr[n + 1];
  float ald = al_d[n];

  float m = -1e30f, s = 0.f;
  for (int i = rs + lane; i < re; i += 64) {
    int src = csr_src[i];
    float e = leaky02(al_s[src] + ald);
    float Mx = fmaxf(m, e);
    s = s * __expf(m - Mx) + __expf(e - Mx);
    m = Mx;
  }
  #pragma unroll
  for (int off = 32; off; off >>= 1) {
    float m2 = __shfl_down(m, off);
    float s2 = __shfl_down(s, off);
    float Mx = fmaxf(m, m2);
    s = s * __expf(m - Mx) + s2 * __expf(m2 - Mx);
    m = Mx;
  }
  m = __shfl(m, 0);
  s = __shfl(s, 0);
  float inv_den = 1.f / (s + 1e-16f);

  float acc0 = 0.f, acc1 = 0.f;
  for (int i = rs; i < re; ++i) {
    int src = csr_src[i];
    float e = leaky02(al_s[src] + ald);
    float wgt = __expf(e - m) * inv_den;
    ushort2 v = *(const ushort2*)&H[(size_t)src * HC + 2 * lane];
    acc0 += wgt * h2f(v.x);
    acc1 += wgt * h2f(v.y);
  }
  float o0 = eluf(acc0 + bias[2 * lane]);
  float o1 = eluf(acc1 + bias[2 * lane + 1]);
  ushort2 o; o.x = f2h(o0); o.y = f2h(o1);
  *(ushort2*)&out[(size_t)n * HC + 2 * lane] = o;
}

// ---------- 7. global max pool (segmented over sorted batch) ----------
static __device__ __forceinline__ unsigned enc_f(float f)
{
  unsigned u = __float_as_uint(f);
  return (u & 0x80000000u) ? ~u : (u | 0x80000000u);
}
static __device__ __forceinline__ float dec_f(unsigned u)
{
  return (u & 0x80000000u) ? __uint_as_float(u & 0x7fffffffu) : __uint_as_float(~u);
}

__global__ void pool_init_kernel(unsigned* __restrict__ p, int n)
{
  int i = blockIdx.x * blockDim.x + threadIdx.x;
  if (i < n) p[i] = 0x00800000u;  // enc(-FLT_MAX)
}

#define PNPB 128   // nodes per pool block
__global__ __launch_bounds__(256)
void pool_seg_kernel(const unsigned short* __restrict__ x, const int* __restrict__ batch,
                     unsigned* __restrict__ pool, int N)
{
  // batch is sorted: keep a running per-channel max, flush one atomic per
  // (graph boundary | chunk end) instead of one atomic per node.
  int cp = (threadIdx.x & 63) * 2;     // channel pair
  int g  = threadIdx.x >> 6;           // node group 0..3
  int n0 = blockIdx.x * PNPB;
  int n1 = min(n0 + PNPB, N);
  int curb = -1;
  float m0 = 0.f, m1 = 0.f;
  for (int n = n0 + g; n < n1; n += 4) {
    int bg = batch[n];
    ushort2 v = *(const ushort2*)&x[(size_t)n * HC + cp];
    float v0 = h2f(v.x), v1 = h2f(v.y);
    if (bg != curb) {
      if (curb >= 0) {
        atomicMax(&pool[curb * HC + cp],     enc_f(m0));
        atomicMax(&pool[curb * HC + cp + 1], enc_f(m1));
      }
      curb = bg; m0 = v0; m1 = v1;
    } else {
      m0 = fmaxf(m0, v0);
      m1 = fmaxf(m1, v1);
    }
  }
  if (curb >= 0) {
    atomicMax(&pool[curb * HC + cp],     enc_f(m0));
    atomicMax(&pool[curb * HC + cp + 1], enc_f(m1));
  }
}

__global__ void pool_final_kernel(const unsigned* __restrict__ pool, float* __restrict__ out, int n)
{
  int i = blockIdx.x * blockDim.x + threadIdx.x;
  if (i < n) out[i] = dec_f(pool[i]);
}

// ---------- launch ----------
extern "C" void kernel_launch(void* const* d_in, const int* in_sizes, int n_in,
                              void* d_out, int out_size, void* d_ws, size_t ws_size,
                              hipStream_t stream)
{
  const float* x_scalar = (const float*)d_in[0];
  const int* i0 = (const int*)d_in[1];
  const int* i1 = (const int*)d_in[2];
  const int* i2 = (const int*)d_in[3];
  const int* i3 = (const int*)d_in[4];
  const int* i4 = (const int*)d_in[5];
  const int* ei = (const int*)d_in[6];
  const int* batch = (const int*)d_in[7];
  const float* e0 = (const float*)d_in[8];
  const float* e1 = (const float*)d_in[9];
  const float* e2 = (const float*)d_in[10];
  const float* e3 = (const float*)d_in[11];
  const float* e4 = (const float*)d_in[12];
  const float* ln_g = (const float*)d_in[13];
  const float* ln_b = (const float*)d_in[14];
  const float* W1 = (const float*)d_in[15];
  const float* as1 = (const float*)d_in[16];
  const float* ad1 = (const float*)d_in[17];
  const float* b1 = (const float*)d_in[18];
  const float* W2 = (const float*)d_in[19];
  const float* as2 = (const float*)d_in[20];
  const float* ad2 = (const float*)d_in[21];
  const float* b2 = (const float*)d_in[22];

  const int N  = in_sizes[0] / SF;
  const int E  = in_sizes[6] / 2;
  const int Et = E + N;
  const int Bg = out_size / HC;
  const int MT = (N + 127) / 128;

  char* w = (char*)d_ws;
  auto alloc = [&](size_t bytes) -> char* {
    char* p = w;
    w += (bytes + 255) & ~(size_t)255;
    return p;
  };
  unsigned short* featsb = (unsigned short*)alloc((size_t)N * KP1 * 2);
  unsigned short* G      = (unsigned short*)alloc((size_t)4 * N * KP1 * 2);
  unsigned short* X2b    = (unsigned short*)alloc((size_t)N * 512 * 2);
  unsigned short* H2b    = (unsigned short*)alloc((size_t)N * HC * 2);
  unsigned short* X3b    = (unsigned short*)alloc((size_t)N * HC * 2);
  unsigned short* W1t    = (unsigned short*)alloc((size_t)512 * KP1 * 2);
  unsigned short* W2t    = (unsigned short*)alloc((size_t)HC * 512 * 2);
  float* vs      = (float*)alloc((size_t)KP1 * 4 * 4);
  float* vd      = (float*)alloc((size_t)KP1 * 4 * 4);
  float* als1    = (float*)alloc((size_t)N * 4 * 4);
  float* ald1    = (float*)alloc((size_t)N * 4 * 4);
  float* als2    = (float*)alloc((size_t)N * 4);
  float* ald2    = (float*)alloc((size_t)N * 4);
  int*   deg     = (int*)alloc((size_t)N * 4);
  int*   rowptr  = (int*)alloc((size_t)(N + 1) * 4);
  int*   fill    = (int*)alloc((size_t)N * 4);
  int*   csr_src = (int*)alloc((size_t)Et * 4);
  unsigned* pool = (unsigned*)alloc((size_t)Bg * HC * 4);

  // constants per call
  pack_wt_kernel<<<(512 * KP1 + 255) / 256, 256, 0, stream>>>(W1, W1t, DIN, 512, KP1);
  pack_wt_kernel<<<(HC * 512 + 255) / 256, 256, 0, stream>>>(W2, W2t, 512, HC, 512);
  prep_attn_kernel<<<DIN, 256, 0, stream>>>(W1, as1, ad1, vs, vd);

  // features + LN + fused layer-1 logits
  feat_ln_kernel<<<N, 256, 0, stream>>>(x_scalar, i0, i1, i2, i3, i4,
                                        e0, e1, e2, e3, e4, ln_g, ln_b,
                                        (const float4*)vs, (const float4*)vd,
                                        featsb, als1, ald1, N);

  // CSR
  zero_kernel<<<(N + 255) / 256, 256, 0, stream>>>(deg, N);
  count_kernel<<<(Et + 255) / 256, 256, 0, stream>>>(ei, E, N, deg);
  scan_kernel<<<1, 1024, 0, stream>>>(deg, rowptr, fill, N);
  scatter_kernel<<<(Et + 255) / 256, 256, 0, stream>>>(ei, E, N, fill, csr_src);

  // layer 1: aggregate feats (4 heads share gather), then per-head GEMM (+b1, ELU)
  agg_feat_kernel<<<N, 64, 0, stream>>>(featsb, (const float4*)als1, (const float4*)ald1,
                                        rowptr, csr_src, G, N);
  gemm_f16_kernel<KP1><<<dim3(1, MT, 4), 256, 0, stream>>>(
      G, W1t, X2b, N, 512, (size_t)N * KP1, (size_t)HC * KP1, HC, b1, 1);

  // layer 2: GEMM (raw H2), logits, aggregate (+b2, ELU)
  gemm_f16_kernel<512><<<dim3(1, MT, 1), 256, 0, stream>>>(
      X2b, W2t, H2b, N, HC, 0, 0, 0, nullptr, 0);
  logits2_kernel<<<N, 128, 0, stream>>>(H2b, as2, ad2, als2, ald2, N);
  agg_h2_kernel<<<N, 64, 0, stream>>>(H2b, als2, ald2, rowptr, csr_src, b2, X3b, N);

  // pool
  pool_init_kernel<<<(Bg * HC + 255) / 256, 256, 0, stream>>>(pool, Bg * HC);
  pool_seg_kernel<<<(N + PNPB - 1) / PNPB, 256, 0, stream>>>(X3b, batch, pool, N);
  pool_final_kernel<<<(Bg * HC + 255) / 256, 256, 0, stream>>>(pool, (float*)d_out, Bg * HC);
}

// Round 5
// 284.112 us; speedup vs baseline: 1.7821x; 1.1180x over previous
//
#include <hip/hip_runtime.h>
#include <math.h>

#define SF 16
#define ED 32
#define LTOK 20
#define DIN 176
#define KP1 192   // DIN padded to multiple of 32
#define HC 128

typedef _Float16 f16x8 __attribute__((ext_vector_type(8)));
typedef float f32x4 __attribute__((ext_vector_type(4)));

static __device__ __forceinline__ float leaky02(float x) { return x >= 0.f ? x : 0.2f * x; }
static __device__ __forceinline__ float eluf(float x)    { return x > 0.f ? x : expm1f(x); }
static __device__ __forceinline__ unsigned short f2h(float f)
{
  _Float16 h = (_Float16)f;
  return __builtin_bit_cast(unsigned short, h);
}
static __device__ __forceinline__ float h2f(unsigned short u)
{
  return (float)__builtin_bit_cast(_Float16, u);
}

// ---------- 0a. pack W [K][Nc] fp32 -> Wt [Nc][KPad] f16 (zero pad) ----------
__global__ void pack_wt_kernel(const float* __restrict__ W, unsigned short* __restrict__ Wt,
                               int K, int Nc, int KPad)
{
  int i = blockIdx.x * blockDim.x + threadIdx.x;
  if (i < Nc * KPad) {
    int n = i / KPad;
    int k = i - n * KPad;
    float v = (k < K) ? W[(size_t)k * Nc + n] : 0.f;
    Wt[i] = f2h(v);
  }
}

// ---------- 0b. v_s[k][h] = sum_c W1[k][h*128+c]*a_s[h][c] (and v_d) ----------
__global__ __launch_bounds__(256)
void prep_attn_kernel(const float* __restrict__ W1, const float* __restrict__ as1,
                      const float* __restrict__ ad1,
                      float* __restrict__ vs, float* __restrict__ vd)
{
  int k = blockIdx.x;                 // 0..175
  int h = threadIdx.x >> 6, lane = threadIdx.x & 63;
  const float* row = W1 + (size_t)k * 512 + h * HC;
  float s = row[lane] * as1[h * HC + lane] + row[lane + 64] * as1[h * HC + lane + 64];
  float d = row[lane] * ad1[h * HC + lane] + row[lane + 64] * ad1[h * HC + lane + 64];
  #pragma unroll
  for (int off = 32; off; off >>= 1) { s += __shfl_down(s, off); d += __shfl_down(d, off); }
  if (lane == 0) { vs[k * 4 + h] = s; vd[k * 4 + h] = d; }
}

// ---------- 1. features + LayerNorm + fused logits; ONE WAVE PER NODE ----------
// Lane l owns channels {l, l+64, l+128}. All reductions are single-wave
// shfl_xor butterflies (ran once per node, vs 4 redundant waves before).
__global__ __launch_bounds__(256)
void feat_ln_kernel(const float* __restrict__ xs,
                    const int* __restrict__ i0, const int* __restrict__ i1,
                    const int* __restrict__ i2, const int* __restrict__ i3,
                    const int* __restrict__ i4,
                    const float* __restrict__ e0, const float* __restrict__ e1,
                    const float* __restrict__ e2, const float* __restrict__ e3,
                    const float* __restrict__ e4,
                    const float* __restrict__ g, const float* __restrict__ b,
                    const float4* __restrict__ vs, const float4* __restrict__ vd,
                    unsigned short* __restrict__ out,
                    float* __restrict__ als, float* __restrict__ ald, int N)
{
  __shared__ int toks[4][5 * LTOK];
  int w = threadIdx.x >> 6, l = threadIdx.x & 63;
  int n = blockIdx.x * 4 + w;
  if (n >= N) return;

  // wave-private token staging (same wave writes then reads its own row;
  // compiler inserts the lgkmcnt dependency wait, no block barrier needed)
  for (int q = l; q < 5 * LTOK; q += 64) {
    int f = q / LTOK, j = q - f * LTOK;
    const int* ip = (f == 0) ? i0 : (f == 1) ? i1 : (f == 2) ? i2 : (f == 3) ? i3 : i4;
    toks[w][q] = ip[n * LTOK + j];
  }

  float v[3];
  #pragma unroll
  for (int r = 0; r < 3; ++r) {
    int c = l + r * 64;
    float val = 0.f;
    if (c < SF) {
      val = xs[n * SF + c];
    } else if (c < DIN) {
      int f  = (c - SF) >> 5;
      int ch = (c - SF) & 31;
      const float* ep = (f == 0) ? e0 : (f == 1) ? e1 : (f == 2) ? e2 : (f == 3) ? e3 : e4;
      // row 0 is a valid padding row: load all 20 unconditionally (stay in flight)
      float vals[LTOK];
      #pragma unroll
      for (int j = 0; j < LTOK; ++j)
        vals[j] = ep[toks[w][f * LTOK + j] * ED + ch];
      float sum = 0.f, cnt = 0.f;
      #pragma unroll
      for (int j = 0; j < LTOK; ++j)
        if (toks[w][f * LTOK + j] != 0) { sum += vals[j]; cnt += 1.f; }
      val = sum / (cnt + 1e-9f);
    }
    v[r] = val;
  }

  float p  = v[0] + v[1] + v[2];
  float p2 = v[0] * v[0] + v[1] * v[1] + v[2] * v[2];
  #pragma unroll
  for (int off = 32; off; off >>= 1) { p += __shfl_xor(p, off); p2 += __shfl_xor(p2, off); }
  float mu   = p * (1.f / DIN);
  float var  = fmaxf(p2 * (1.f / DIN) - mu * mu, 0.f);
  float rstd = rsqrtf(var + 1e-5f);

  float pr[8] = {0.f, 0.f, 0.f, 0.f, 0.f, 0.f, 0.f, 0.f};
  #pragma unroll
  for (int r = 0; r < 3; ++r) {
    int c = l + r * 64;
    float y = 0.f;
    if (c < DIN) {
      y = (v[r] - mu) * rstd * g[c] + b[c];
      float4 s4 = vs[c], d4 = vd[c];
      pr[0] += y * s4.x; pr[1] += y * s4.y; pr[2] += y * s4.z; pr[3] += y * s4.w;
      pr[4] += y * d4.x; pr[5] += y * d4.y; pr[6] += y * d4.z; pr[7] += y * d4.w;
    }
    if (c < KP1) out[(size_t)n * KP1 + c] = f2h(y);
  }
  #pragma unroll
  for (int j = 0; j < 8; ++j)
    #pragma unroll
    for (int off = 32; off; off >>= 1) pr[j] += __shfl_xor(pr[j], off);
  if (l == 0) {
    als[n * 4 + 0] = pr[0]; als[n * 4 + 1] = pr[1];
    als[n * 4 + 2] = pr[2]; als[n * 4 + 3] = pr[3];
    ald[n * 4 + 0] = pr[4]; ald[n * 4 + 1] = pr[5];
    ald[n * 4 + 2] = pr[6]; ald[n * 4 + 3] = pr[7];
  }
}

// ---------- 2. CSR build ----------
__global__ void zero_kernel(int* __restrict__ p, int n)
{
  int i = blockIdx.x * blockDim.x + threadIdx.x;
  if (i < n) p[i] = 0;
}

__global__ void count_kernel(const int* __restrict__ ei, int E, int N, int* __restrict__ deg)
{
  int e = blockIdx.x * blockDim.x + threadIdx.x;
  if (e < E + N) {
    int dst = (e < E) ? ei[E + e] : (e - E);
    atomicAdd(&deg[dst], 1);
  }
}

__global__ __launch_bounds__(1024)
void scan_kernel(const int* __restrict__ deg, int* __restrict__ rowptr,
                 int* __restrict__ fill, int N)
{
  __shared__ int sums[1024];
  int t = threadIdx.x;
  int CH = (N + 1023) >> 10;
  int base = t * CH;
  int s = 0;
  for (int i = 0; i < CH; ++i) if (base + i < N) s += deg[base + i];
  sums[t] = s;
  __syncthreads();
  for (int off = 1; off < 1024; off <<= 1) {
    int v = (t >= off) ? sums[t - off] : 0;
    __syncthreads();
    sums[t] += v;
    __syncthreads();
  }
  int run = sums[t] - s;  // exclusive prefix
  for (int i = 0; i < CH; ++i) {
    if (base + i < N) {
      rowptr[base + i] = run;
      fill[base + i]   = run;
      run += deg[base + i];
    }
  }
  if (t == 1023) rowptr[N] = run;
}

__global__ void scatter_kernel(const int* __restrict__ ei, int E, int N,
                               int* __restrict__ fill, int* __restrict__ csr_src)
{
  int e = blockIdx.x * blockDim.x + threadIdx.x;
  if (e < E + N) {
    int src, dst;
    if (e < E) { src = ei[e]; dst = ei[E + e]; }
    else       { src = dst = e - E; }
    int pos = atomicAdd(&fill[dst], 1);
    csr_src[pos] = src;
  }
}

// ---------- 3. layer-1 aggregation over FEATURES (one wave per dst, 4 heads share gather) ----------
__global__ __launch_bounds__(64)
void agg_feat_kernel(const unsigned short* __restrict__ F,   // [N][KP1] f16
                     const float4* __restrict__ als, const float4* __restrict__ ald,
                     const int* __restrict__ rowptr, const int* __restrict__ csr_src,
                     unsigned short* __restrict__ G, int N)  // [4][N][KP1] f16
{
  int n = blockIdx.x, lane = threadIdx.x;
  int rs = rowptr[n], re = rowptr[n + 1];
  float4 ad4 = ald[n];
  float aldv[4] = { ad4.x, ad4.y, ad4.z, ad4.w };

  float m[4], s[4];
  #pragma unroll
  for (int h = 0; h < 4; ++h) { m[h] = -1e30f; s[h] = 0.f; }
  for (int i = rs + lane; i < re; i += 64) {
    int src = csr_src[i];
    float4 a4 = als[src];
    float av[4] = { a4.x, a4.y, a4.z, a4.w };
    #pragma unroll
    for (int h = 0; h < 4; ++h) {
      float e = leaky02(av[h] + aldv[h]);
      float Mx = fmaxf(m[h], e);
      s[h] = s[h] * __expf(m[h] - Mx) + __expf(e - Mx);
      m[h] = Mx;
    }
  }
  #pragma unroll
  for (int off = 32; off; off >>= 1) {
    #pragma unroll
    for (int h = 0; h < 4; ++h) {
      float m2 = __shfl_down(m[h], off);
      float s2 = __shfl_down(s[h], off);
      float Mx = fmaxf(m[h], m2);
      s[h] = s[h] * __expf(m[h] - Mx) + s2 * __expf(m2 - Mx);
      m[h] = Mx;
    }
  }
  float inv[4];
  #pragma unroll
  for (int h = 0; h < 4; ++h) {
    m[h] = __shfl(m[h], 0);
    float sh = __shfl(s[h], 0);
    inv[h] = 1.f / (sh + 1e-16f);
  }

  float acc[4][4] = {};
  int k4 = lane * 4;
  bool active = lane < 44;                 // 44*4 = 176 real channels
  const unsigned short* Fb = F + k4;
  for (int i = rs; i < re; ++i) {
    int src = csr_src[i];
    float4 a4 = als[src];
    float av[4] = { a4.x, a4.y, a4.z, a4.w };
    float w[4];
    #pragma unroll
    for (int h = 0; h < 4; ++h)
      w[h] = __expf(leaky02(av[h] + aldv[h]) - m[h]) * inv[h];
    if (active) {
      ushort4 vv = *(const ushort4*)(Fb + (size_t)src * KP1);
      float f0 = h2f(vv.x), f1 = h2f(vv.y), f2v = h2f(vv.z), f3 = h2f(vv.w);
      #pragma unroll
      for (int h = 0; h < 4; ++h) {
        acc[h][0] += w[h] * f0;  acc[h][1] += w[h] * f1;
        acc[h][2] += w[h] * f2v; acc[h][3] += w[h] * f3;
      }
    }
  }
  if (lane < 48) {                         // also writes zero tail [176,192)
    #pragma unroll
    for (int h = 0; h < 4; ++h) {
      ushort4 o;
      o.x = f2h(acc[h][0]); o.y = f2h(acc[h][1]);
      o.z = f2h(acc[h][2]); o.w = f2h(acc[h][3]);
      *(ushort4*)&G[((size_t)h * N + n) * KP1 + k4] = o;
    }
  }
}

// ---------- 4. MFMA f16 GEMM: C[:, zcols] = A_z[M,KPad] @ Bt_z[128,KPad]^T (+bias, ELU) ----------
template<int KPad>
__global__ __launch_bounds__(256)
void gemm_f16_kernel(const unsigned short* __restrict__ A, const unsigned short* __restrict__ Bt,
                     unsigned short* __restrict__ C, int M, int Nc,
                     size_t aStrideZ, size_t bStrideZ, int cColStrideZ,
                     const float* __restrict__ bias, int act)
{
  A  += blockIdx.z * aStrideZ;
  Bt += blockIdx.z * bStrideZ;
  int colZ = blockIdx.z * cColStrideZ;

  __shared__ __align__(16) unsigned short As[4][128][8];
  __shared__ __align__(16) unsigned short Bs[4][128][8];
  int tid  = threadIdx.x;
  int lane = tid & 63, wave = tid >> 6;
  int wm = (wave >> 1) << 6, wn = (wave & 1) << 6;
  int bm = blockIdx.y << 7, bn = blockIdx.x << 7;

  int srow = tid >> 1;
  int skc  = (tid & 1) << 1;
  const unsigned short* Arow = A  + (size_t)(bm + srow) * KPad + skc * 8;
  const unsigned short* Brow = Bt + (size_t)(bn + srow) * KPad + skc * 8;
  bool aok = (bm + srow) < M;

  f32x4 acc[4][4];
  #pragma unroll
  for (int m = 0; m < 4; ++m)
    #pragma unroll
    for (int n2 = 0; n2 < 4; ++n2) acc[m][n2] = (f32x4){0.f, 0.f, 0.f, 0.f};

  int kc  = lane >> 4;
  int r16 = lane & 15;

  for (int k0 = 0; k0 < KPad; k0 += 32) {
    int4 av0 = make_int4(0, 0, 0, 0), av1 = make_int4(0, 0, 0, 0);
    if (aok) {
      av0 = *(const int4*)(Arow + k0);
      av1 = *(const int4*)(Arow + k0 + 8);
    }
    int4 bv0 = *(const int4*)(Brow + k0);
    int4 bv1 = *(const int4*)(Brow + k0 + 8);
    __syncthreads();
    *(int4*)&As[skc][srow][0]     = av0;
    *(int4*)&As[skc + 1][srow][0] = av1;
    *(int4*)&Bs[skc][srow][0]     = bv0;
    *(int4*)&Bs[skc + 1][srow][0] = bv1;
    __syncthreads();

    f16x8 af[4], bfr[4];
    #pragma unroll
    for (int m = 0; m < 4; ++m)  af[m]  = *(const f16x8*)&As[kc][wm + m * 16 + r16][0];
    #pragma unroll
    for (int n2 = 0; n2 < 4; ++n2) bfr[n2] = *(const f16x8*)&Bs[kc][wn + n2 * 16 + r16][0];
    #pragma unroll
    for (int m = 0; m < 4; ++m)
      #pragma unroll
      for (int n2 = 0; n2 < 4; ++n2)
        acc[m][n2] = __builtin_amdgcn_mfma_f32_16x16x32_f16(af[m], bfr[n2], acc[m][n2], 0, 0, 0);
  }

  int rq = lane >> 4;
  #pragma unroll
  for (int m = 0; m < 4; ++m) {
    #pragma unroll
    for (int r = 0; r < 4; ++r) {
      int row = bm + wm + m * 16 + rq * 4 + r;
      if (row < M) {
        #pragma unroll
        for (int n2 = 0; n2 < 4; ++n2) {
          int col = colZ + bn + wn + n2 * 16 + r16;
          float val = acc[m][n2][r];
          if (bias) val += bias[col];
          if (act)  val = eluf(val);
          C[(size_t)row * Nc + col] = f2h(val);
        }
      }
    }
  }
}

// ---------- 5. layer-2 attention logits from f16 H2 ----------
__global__ __launch_bounds__(128)
void logits2_kernel(const unsigned short* __restrict__ H,
                    const float* __restrict__ a_s, const float* __restrict__ a_d,
                    float* __restrict__ al_s, float* __restrict__ al_d, int N)
{
  int n = blockIdx.x, t = threadIdx.x;
  int wv = t >> 6, lane = t & 63;
  __shared__ float tmp[2][2];
  float hv = h2f(H[(size_t)n * HC + t]);
  float ps = hv * a_s[t];
  float pd = hv * a_d[t];
  #pragma unroll
  for (int off = 32; off; off >>= 1) { ps += __shfl_down(ps, off); pd += __shfl_down(pd, off); }
  if (lane == 0) { tmp[0][wv] = ps; tmp[1][wv] = pd; }
  __syncthreads();
  if (t == 0) {
    al_s[n] = tmp[0][0] + tmp[0][1];
    al_d[n] = tmp[1][0] + tmp[1][1];
  }
}

// ---------- 6. layer-2 aggregation (H2 gather) + bias + ELU ----------
__global__ __launch_bounds__(64)
void agg_h2_kernel(const unsigned short* __restrict__ H,
                   const float* __restrict__ al_s, const float* __restrict__ al_d,
                   const int* __restrict__ rowptr, const int* __restrict__ csr_src,
                   const float* __restrict__ bias, unsigned short* __restrict__ out, int N)
{
  int n = blockIdx.x;
  int lane = threadIdx.x;
  int rs = rowptr[n], re = rowptr[n + 1];
  float ald = al_d[n];

  float m = -1e30f, s = 0.f;
  for (int i = rs + lane; i < re; i += 64) {
    int src = csr_src[i];
    float e = leaky02(al_s[src] + ald);
    float Mx = fmaxf(m, e);
    s = s * __expf(m - Mx) + __expf(e - Mx);
    m = Mx;
  }
  #pragma unroll
  for (int off = 32; off; off >>= 1) {
    float m2 = __shfl_down(m, off);
    float s2 = __shfl_down(s, off);
    float Mx = fmaxf(m, m2);
    s = s * __expf(m - Mx) + s2 * __expf(m2 - Mx);
    m = Mx;
  }
  m = __shfl(m, 0);
  s = __shfl(s, 0);
  float inv_den = 1.f / (s + 1e-16f);

  float acc0 = 0.f, acc1 = 0.f;
  for (int i = rs; i < re; ++i) {
    int src = csr_src[i];
    float e = leaky02(al_s[src] + ald);
    float wgt = __expf(e - m) * inv_den;
    ushort2 v = *(const ushort2*)&H[(size_t)src * HC + 2 * lane];
    acc0 += wgt * h2f(v.x);
    acc1 += wgt * h2f(v.y);
  }
  float o0 = eluf(acc0 + bias[2 * lane]);
  float o1 = eluf(acc1 + bias[2 * lane + 1]);
  ushort2 o; o.x = f2h(o0); o.y = f2h(o1);
  *(ushort2*)&out[(size_t)n * HC + 2 * lane] = o;
}

// ---------- 7. global max pool (segmented over sorted batch) ----------
static __device__ __forceinline__ unsigned enc_f(float f)
{
  unsigned u = __float_as_uint(f);
  return (u & 0x80000000u) ? ~u : (u | 0x80000000u);
}
static __device__ __forceinline__ float dec_f(unsigned u)
{
  return (u & 0x80000000u) ? __uint_as_float(u & 0x7fffffffu) : __uint_as_float(~u);
}

__global__ void pool_init_kernel(unsigned* __restrict__ p, int n)
{
  int i = blockIdx.x * blockDim.x + threadIdx.x;
  if (i < n) p[i] = 0x00800000u;  // enc(-FLT_MAX)
}

#define PNPB 128   // nodes per pool block
__global__ __launch_bounds__(256)
void pool_seg_kernel(const unsigned short* __restrict__ x, const int* __restrict__ batch,
                     unsigned* __restrict__ pool, int N)
{
  // batch is sorted: keep a running per-channel max, flush one atomic per
  // (graph boundary | chunk end) instead of one atomic per node.
  int cp = (threadIdx.x & 63) * 2;     // channel pair
  int g  = threadIdx.x >> 6;           // node group 0..3
  int n0 = blockIdx.x * PNPB;
  int n1 = min(n0 + PNPB, N);
  int curb = -1;
  float m0 = 0.f, m1 = 0.f;
  for (int n = n0 + g; n < n1; n += 4) {
    int bg = batch[n];
    ushort2 v = *(const ushort2*)&x[(size_t)n * HC + cp];
    float v0 = h2f(v.x), v1 = h2f(v.y);
    if (bg != curb) {
      if (curb >= 0) {
        atomicMax(&pool[curb * HC + cp],     enc_f(m0));
        atomicMax(&pool[curb * HC + cp + 1], enc_f(m1));
      }
      curb = bg; m0 = v0; m1 = v1;
    } else {
      m0 = fmaxf(m0, v0);
      m1 = fmaxf(m1, v1);
    }
  }
  if (curb >= 0) {
    atomicMax(&pool[curb * HC + cp],     enc_f(m0));
    atomicMax(&pool[curb * HC + cp + 1], enc_f(m1));
  }
}

__global__ void pool_final_kernel(const unsigned* __restrict__ pool, float* __restrict__ out, int n)
{
  int i = blockIdx.x * blockDim.x + threadIdx.x;
  if (i < n) out[i] = dec_f(pool[i]);
}

// ---------- launch ----------
extern "C" void kernel_launch(void* const* d_in, const int* in_sizes, int n_in,
                              void* d_out, int out_size, void* d_ws, size_t ws_size,
                              hipStream_t stream)
{
  const float* x_scalar = (const float*)d_in[0];
  const int* i0 = (const int*)d_in[1];
  const int* i1 = (const int*)d_in[2];
  const int* i2 = (const int*)d_in[3];
  const int* i3 = (const int*)d_in[4];
  const int* i4 = (const int*)d_in[5];
  const int* ei = (const int*)d_in[6];
  const int* batch = (const int*)d_in[7];
  const float* e0 = (const float*)d_in[8];
  const float* e1 = (const float*)d_in[9];
  const float* e2 = (const float*)d_in[10];
  const float* e3 = (const float*)d_in[11];
  const float* e4 = (const float*)d_in[12];
  const float* ln_g = (const float*)d_in[13];
  const float* ln_b = (const float*)d_in[14];
  const float* W1 = (const float*)d_in[15];
  const float* as1 = (const float*)d_in[16];
  const float* ad1 = (const float*)d_in[17];
  const float* b1 = (const float*)d_in[18];
  const float* W2 = (const float*)d_in[19];
  const float* as2 = (const float*)d_in[20];
  const float* ad2 = (const float*)d_in[21];
  const float* b2 = (const float*)d_in[22];

  const int N  = in_sizes[0] / SF;
  const int E  = in_sizes[6] / 2;
  const int Et = E + N;
  const int Bg = out_size / HC;
  const int MT = (N + 127) / 128;

  char* w = (char*)d_ws;
  auto alloc = [&](size_t bytes) -> char* {
    char* p = w;
    w += (bytes + 255) & ~(size_t)255;
    return p;
  };
  unsigned short* featsb = (unsigned short*)alloc((size_t)N * KP1 * 2);
  unsigned short* G      = (unsigned short*)alloc((size_t)4 * N * KP1 * 2);
  unsigned short* X2b    = (unsigned short*)alloc((size_t)N * 512 * 2);
  unsigned short* H2b    = (unsigned short*)alloc((size_t)N * HC * 2);
  unsigned short* X3b    = (unsigned short*)alloc((size_t)N * HC * 2);
  unsigned short* W1t    = (unsigned short*)alloc((size_t)512 * KP1 * 2);
  unsigned short* W2t    = (unsigned short*)alloc((size_t)HC * 512 * 2);
  float* vs      = (float*)alloc((size_t)KP1 * 4 * 4);
  float* vd      = (float*)alloc((size_t)KP1 * 4 * 4);
  float* als1    = (float*)alloc((size_t)N * 4 * 4);
  float* ald1    = (float*)alloc((size_t)N * 4 * 4);
  float* als2    = (float*)alloc((size_t)N * 4);
  float* ald2    = (float*)alloc((size_t)N * 4);
  int*   deg     = (int*)alloc((size_t)N * 4);
  int*   rowptr  = (int*)alloc((size_t)(N + 1) * 4);
  int*   fill    = (int*)alloc((size_t)N * 4);
  int*   csr_src = (int*)alloc((size_t)Et * 4);
  unsigned* pool = (unsigned*)alloc((size_t)Bg * HC * 4);

  // constants per call
  pack_wt_kernel<<<(512 * KP1 + 255) / 256, 256, 0, stream>>>(W1, W1t, DIN, 512, KP1);
  pack_wt_kernel<<<(HC * 512 + 255) / 256, 256, 0, stream>>>(W2, W2t, 512, HC, 512);
  prep_attn_kernel<<<DIN, 256, 0, stream>>>(W1, as1, ad1, vs, vd);

  // features + LN + fused layer-1 logits (one wave per node, 4 nodes/block)
  feat_ln_kernel<<<(N + 3) / 4, 256, 0, stream>>>(x_scalar, i0, i1, i2, i3, i4,
                                                  e0, e1, e2, e3, e4, ln_g, ln_b,
                                                  (const float4*)vs, (const float4*)vd,
                                                  featsb, als1, ald1, N);

  // CSR
  zero_kernel<<<(N + 255) / 256, 256, 0, stream>>>(deg, N);
  count_kernel<<<(Et + 255) / 256, 256, 0, stream>>>(ei, E, N, deg);
  scan_kernel<<<1, 1024, 0, stream>>>(deg, rowptr, fill, N);
  scatter_kernel<<<(Et + 255) / 256, 256, 0, stream>>>(ei, E, N, fill, csr_src);

  // layer 1: aggregate feats (4 heads share gather), then per-head GEMM (+b1, ELU)
  agg_feat_kernel<<<N, 64, 0, stream>>>(featsb, (const float4*)als1, (const float4*)ald1,
                                        rowptr, csr_src, G, N);
  gemm_f16_kernel<KP1><<<dim3(1, MT, 4), 256, 0, stream>>>(
      G, W1t, X2b, N, 512, (size_t)N * KP1, (size_t)HC * KP1, HC, b1, 1);

  // layer 2: GEMM (raw H2), logits, aggregate (+b2, ELU)
  gemm_f16_kernel<512><<<dim3(1, MT, 1), 256, 0, stream>>>(
      X2b, W2t, H2b, N, HC, 0, 0, 0, nullptr, 0);
  logits2_kernel<<<N, 128, 0, stream>>>(H2b, as2, ad2, als2, ald2, N);
  agg_h2_kernel<<<N, 64, 0, stream>>>(H2b, als2, ald2, rowptr, csr_src, b2, X3b, N);

  // pool
  pool_init_kernel<<<(Bg * HC + 255) / 256, 256, 0, stream>>>(pool, Bg * HC);
  pool_seg_kernel<<<(N + PNPB - 1) / PNPB, 256, 0, stream>>>(X3b, batch, pool, N);
  pool_final_kernel<<<(Bg * HC + 255) / 256, 256, 0, stream>>>(pool, (float*)d_out, Bg * HC);
}

// Round 6
// 278.976 us; speedup vs baseline: 1.8149x; 1.0184x over previous
//
#include <hip/hip_runtime.h>
#include <math.h>

#define SF 16
#define ED 32
#define LTOK 20
#define DIN 176
#define KP1 192   // DIN padded to multiple of 32
#define HC 128

typedef _Float16 f16x8 __attribute__((ext_vector_type(8)));
typedef float f32x4 __attribute__((ext_vector_type(4)));

static __device__ __forceinline__ float leaky02(float x) { return x >= 0.f ? x : 0.2f * x; }
static __device__ __forceinline__ float eluf(float x)    { return x > 0.f ? x : expm1f(x); }
static __device__ __forceinline__ unsigned short f2h(float f)
{
  _Float16 h = (_Float16)f;
  return __builtin_bit_cast(unsigned short, h);
}
static __device__ __forceinline__ float h2f(unsigned short u)
{
  return (float)__builtin_bit_cast(_Float16, u);
}
static __device__ __forceinline__ float readlane_f(float v, int j)
{
  return __int_as_float(__builtin_amdgcn_readlane(__float_as_int(v), j));
}

// ---------- 0a. pack W [K][Nc] fp32 -> Wt [Nc][KPad] f16 (zero pad) ----------
__global__ void pack_wt_kernel(const float* __restrict__ W, unsigned short* __restrict__ Wt,
                               int K, int Nc, int KPad)
{
  int i = blockIdx.x * blockDim.x + threadIdx.x;
  if (i < Nc * KPad) {
    int n = i / KPad;
    int k = i - n * KPad;
    float v = (k < K) ? W[(size_t)k * Nc + n] : 0.f;
    Wt[i] = f2h(v);
  }
}

// ---------- 0b. v_s[k][h] = sum_c W1[k][h*128+c]*a_s[h][c] (and v_d) ----------
__global__ __launch_bounds__(256)
void prep_attn_kernel(const float* __restrict__ W1, const float* __restrict__ as1,
                      const float* __restrict__ ad1,
                      float* __restrict__ vs, float* __restrict__ vd)
{
  int k = blockIdx.x;                 // 0..175
  int h = threadIdx.x >> 6, lane = threadIdx.x & 63;
  const float* row = W1 + (size_t)k * 512 + h * HC;
  float s = row[lane] * as1[h * HC + lane] + row[lane + 64] * as1[h * HC + lane + 64];
  float d = row[lane] * ad1[h * HC + lane] + row[lane + 64] * ad1[h * HC + lane + 64];
  #pragma unroll
  for (int off = 32; off; off >>= 1) { s += __shfl_down(s, off); d += __shfl_down(d, off); }
  if (lane == 0) { vs[k * 4 + h] = s; vd[k * 4 + h] = d; }
}

// ---------- 1. features + LayerNorm + fused logits; ONE WAVE PER NODE ----------
__global__ __launch_bounds__(256)
void feat_ln_kernel(const float* __restrict__ xs,
                    const int* __restrict__ i0, const int* __restrict__ i1,
                    const int* __restrict__ i2, const int* __restrict__ i3,
                    const int* __restrict__ i4,
                    const float* __restrict__ e0, const float* __restrict__ e1,
                    const float* __restrict__ e2, const float* __restrict__ e3,
                    const float* __restrict__ e4,
                    const float* __restrict__ g, const float* __restrict__ b,
                    const float4* __restrict__ vs, const float4* __restrict__ vd,
                    unsigned short* __restrict__ out,
                    float* __restrict__ als, float* __restrict__ ald, int N)
{
  __shared__ int toks[4][5 * LTOK];
  int w = threadIdx.x >> 6, l = threadIdx.x & 63;
  int n = blockIdx.x * 4 + w;
  if (n >= N) return;

  for (int q = l; q < 5 * LTOK; q += 64) {
    int f = q / LTOK, j = q - f * LTOK;
    const int* ip = (f == 0) ? i0 : (f == 1) ? i1 : (f == 2) ? i2 : (f == 3) ? i3 : i4;
    toks[w][q] = ip[n * LTOK + j];
  }

  float v[3];
  #pragma unroll
  for (int r = 0; r < 3; ++r) {
    int c = l + r * 64;
    float val = 0.f;
    if (c < SF) {
      val = xs[n * SF + c];
    } else if (c < DIN) {
      int f  = (c - SF) >> 5;
      int ch = (c - SF) & 31;
      const float* ep = (f == 0) ? e0 : (f == 1) ? e1 : (f == 2) ? e2 : (f == 3) ? e3 : e4;
      float vals[LTOK];
      #pragma unroll
      for (int j = 0; j < LTOK; ++j)
        vals[j] = ep[toks[w][f * LTOK + j] * ED + ch];
      float sum = 0.f, cnt = 0.f;
      #pragma unroll
      for (int j = 0; j < LTOK; ++j)
        if (toks[w][f * LTOK + j] != 0) { sum += vals[j]; cnt += 1.f; }
      val = sum / (cnt + 1e-9f);
    }
    v[r] = val;
  }

  float p  = v[0] + v[1] + v[2];
  float p2 = v[0] * v[0] + v[1] * v[1] + v[2] * v[2];
  #pragma unroll
  for (int off = 32; off; off >>= 1) { p += __shfl_xor(p, off); p2 += __shfl_xor(p2, off); }
  float mu   = p * (1.f / DIN);
  float var  = fmaxf(p2 * (1.f / DIN) - mu * mu, 0.f);
  float rstd = rsqrtf(var + 1e-5f);

  float pr[8] = {0.f, 0.f, 0.f, 0.f, 0.f, 0.f, 0.f, 0.f};
  #pragma unroll
  for (int r = 0; r < 3; ++r) {
    int c = l + r * 64;
    float y = 0.f;
    if (c < DIN) {
      y = (v[r] - mu) * rstd * g[c] + b[c];
      float4 s4 = vs[c], d4 = vd[c];
      pr[0] += y * s4.x; pr[1] += y * s4.y; pr[2] += y * s4.z; pr[3] += y * s4.w;
      pr[4] += y * d4.x; pr[5] += y * d4.y; pr[6] += y * d4.z; pr[7] += y * d4.w;
    }
    if (c < KP1) out[(size_t)n * KP1 + c] = f2h(y);
  }
  #pragma unroll
  for (int j = 0; j < 8; ++j)
    #pragma unroll
    for (int off = 32; off; off >>= 1) pr[j] += __shfl_xor(pr[j], off);
  if (l == 0) {
    als[n * 4 + 0] = pr[0]; als[n * 4 + 1] = pr[1];
    als[n * 4 + 2] = pr[2]; als[n * 4 + 3] = pr[3];
    ald[n * 4 + 0] = pr[4]; ald[n * 4 + 1] = pr[5];
    ald[n * 4 + 2] = pr[6]; ald[n * 4 + 3] = pr[7];
  }
}

// ---------- 2. CSR build ----------
__global__ void zero_kernel(int* __restrict__ p, int n)
{
  int i = blockIdx.x * blockDim.x + threadIdx.x;
  if (i < n) p[i] = 0;
}

__global__ void count_kernel(const int* __restrict__ ei, int E, int N, int* __restrict__ deg)
{
  int e = blockIdx.x * blockDim.x + threadIdx.x;
  if (e < E + N) {
    int dst = (e < E) ? ei[E + e] : (e - E);
    atomicAdd(&deg[dst], 1);
  }
}

__global__ __launch_bounds__(1024)
void scan_kernel(const int* __restrict__ deg, int* __restrict__ rowptr,
                 int* __restrict__ fill, int N)
{
  __shared__ int sums[1024];
  int t = threadIdx.x;
  int CH = (N + 1023) >> 10;
  int base = t * CH;
  int s = 0;
  for (int i = 0; i < CH; ++i) if (base + i < N) s += deg[base + i];
  sums[t] = s;
  __syncthreads();
  for (int off = 1; off < 1024; off <<= 1) {
    int v = (t >= off) ? sums[t - off] : 0;
    __syncthreads();
    sums[t] += v;
    __syncthreads();
  }
  int run = sums[t] - s;  // exclusive prefix
  for (int i = 0; i < CH; ++i) {
    if (base + i < N) {
      rowptr[base + i] = run;
      fill[base + i]   = run;
      run += deg[base + i];
    }
  }
  if (t == 1023) rowptr[N] = run;
}

__global__ void scatter_kernel(const int* __restrict__ ei, int E, int N,
                               int* __restrict__ fill, int* __restrict__ csr_src)
{
  int e = blockIdx.x * blockDim.x + threadIdx.x;
  if (e < E + N) {
    int src, dst;
    if (e < E) { src = ei[e]; dst = ei[E + e]; }
    else       { src = dst = e - E; }
    int pos = atomicAdd(&fill[dst], 1);
    csr_src[pos] = src;
  }
}

// ---------- 3. layer-1 aggregation over FEATURES ----------
// 4 waves/block (one node per wave). Chunk-parallel weights: pass A computes
// 64 edge weights (one per lane), pass B broadcasts via v_readlane (SGPR) and
// does only the gather + FMA.
__global__ __launch_bounds__(256)
void agg_feat_kernel(const unsigned short* __restrict__ F,   // [N][KP1] f16
                     const float4* __restrict__ als, const float4* __restrict__ ald,
                     const int* __restrict__ rowptr, const int* __restrict__ csr_src,
                     unsigned short* __restrict__ G, int N)  // [4][N][KP1] f16
{
  int wv = threadIdx.x >> 6, lane = threadIdx.x & 63;
  int n = blockIdx.x * 4 + wv;
  if (n >= N) return;
  int rs = __builtin_amdgcn_readfirstlane(rowptr[n]);
  int re = __builtin_amdgcn_readfirstlane(rowptr[n + 1]);
  float4 ad4 = ald[n];
  float aldv[4] = { ad4.x, ad4.y, ad4.z, ad4.w };

  // pass 1: online (max, sum) strided across lanes
  float m[4], s[4];
  #pragma unroll
  for (int h = 0; h < 4; ++h) { m[h] = -1e30f; s[h] = 0.f; }
  for (int i = rs + lane; i < re; i += 64) {
    int src = csr_src[i];
    float4 a4 = als[src];
    float av[4] = { a4.x, a4.y, a4.z, a4.w };
    #pragma unroll
    for (int h = 0; h < 4; ++h) {
      float e = leaky02(av[h] + aldv[h]);
      float Mx = fmaxf(m[h], e);
      s[h] = s[h] * __expf(m[h] - Mx) + __expf(e - Mx);
      m[h] = Mx;
    }
  }
  #pragma unroll
  for (int off = 32; off; off >>= 1) {
    #pragma unroll
    for (int h = 0; h < 4; ++h) {
      float m2 = __shfl_down(m[h], off);
      float s2 = __shfl_down(s[h], off);
      float Mx = fmaxf(m[h], m2);
      s[h] = s[h] * __expf(m[h] - Mx) + s2 * __expf(m2 - Mx);
      m[h] = Mx;
    }
  }
  float inv[4];
  #pragma unroll
  for (int h = 0; h < 4; ++h) {
    m[h] = __shfl(m[h], 0);
    float sh = __shfl(s[h], 0);
    inv[h] = 1.f / (sh + 1e-16f);
  }

  float acc[4][4] = {};
  int k4 = lane * 4;
  bool active = lane < 44;                 // 44*4 = 176 real channels
  for (int c0 = rs; c0 < re; c0 += 64) {
    int cnt = min(64, re - c0);
    // pass A: one edge per lane -> normalized weights in registers
    int srcA = 0;
    float wA[4] = {0.f, 0.f, 0.f, 0.f};
    if (lane < cnt) {
      srcA = csr_src[c0 + lane];
      float4 a4 = als[srcA];
      float av[4] = { a4.x, a4.y, a4.z, a4.w };
      #pragma unroll
      for (int h = 0; h < 4; ++h)
        wA[h] = __expf(leaky02(av[h] + aldv[h]) - m[h]) * inv[h];
    }
    // pass B: broadcast (SGPR) + gather + FMA only
    for (int j = 0; j < cnt; ++j) {
      int src = __builtin_amdgcn_readlane(srcA, j);
      float w0 = readlane_f(wA[0], j);
      float w1 = readlane_f(wA[1], j);
      float w2 = readlane_f(wA[2], j);
      float w3 = readlane_f(wA[3], j);
      if (active) {
        ushort4 vv = *(const ushort4*)(F + (size_t)src * KP1 + k4);
        float f0 = h2f(vv.x), f1 = h2f(vv.y), f2v = h2f(vv.z), f3 = h2f(vv.w);
        acc[0][0] += w0 * f0; acc[0][1] += w0 * f1; acc[0][2] += w0 * f2v; acc[0][3] += w0 * f3;
        acc[1][0] += w1 * f0; acc[1][1] += w1 * f1; acc[1][2] += w1 * f2v; acc[1][3] += w1 * f3;
        acc[2][0] += w2 * f0; acc[2][1] += w2 * f1; acc[2][2] += w2 * f2v; acc[2][3] += w2 * f3;
        acc[3][0] += w3 * f0; acc[3][1] += w3 * f1; acc[3][2] += w3 * f2v; acc[3][3] += w3 * f3;
      }
    }
  }
  if (lane < 48) {                         // also writes zero tail [176,192)
    #pragma unroll
    for (int h = 0; h < 4; ++h) {
      ushort4 o;
      o.x = f2h(acc[h][0]); o.y = f2h(acc[h][1]);
      o.z = f2h(acc[h][2]); o.w = f2h(acc[h][3]);
      *(ushort4*)&G[((size_t)h * N + n) * KP1 + k4] = o;
    }
  }
}

// ---------- 4. MFMA f16 GEMM: C[:, zcols] = A_z[M,KPad] @ Bt_z[128,KPad]^T (+bias, ELU) ----------
template<int KPad>
__global__ __launch_bounds__(256)
void gemm_f16_kernel(const unsigned short* __restrict__ A, const unsigned short* __restrict__ Bt,
                     unsigned short* __restrict__ C, int M, int Nc,
                     size_t aStrideZ, size_t bStrideZ, int cColStrideZ,
                     const float* __restrict__ bias, int act)
{
  A  += blockIdx.z * aStrideZ;
  Bt += blockIdx.z * bStrideZ;
  int colZ = blockIdx.z * cColStrideZ;

  __shared__ __align__(16) unsigned short As[4][128][8];
  __shared__ __align__(16) unsigned short Bs[4][128][8];
  int tid  = threadIdx.x;
  int lane = tid & 63, wave = tid >> 6;
  int wm = (wave >> 1) << 6, wn = (wave & 1) << 6;
  int bm = blockIdx.y << 7, bn = blockIdx.x << 7;

  int srow = tid >> 1;
  int skc  = (tid & 1) << 1;
  const unsigned short* Arow = A  + (size_t)(bm + srow) * KPad + skc * 8;
  const unsigned short* Brow = Bt + (size_t)(bn + srow) * KPad + skc * 8;
  bool aok = (bm + srow) < M;

  f32x4 acc[4][4];
  #pragma unroll
  for (int m = 0; m < 4; ++m)
    #pragma unroll
    for (int n2 = 0; n2 < 4; ++n2) acc[m][n2] = (f32x4){0.f, 0.f, 0.f, 0.f};

  int kc  = lane >> 4;
  int r16 = lane & 15;

  for (int k0 = 0; k0 < KPad; k0 += 32) {
    int4 av0 = make_int4(0, 0, 0, 0), av1 = make_int4(0, 0, 0, 0);
    if (aok) {
      av0 = *(const int4*)(Arow + k0);
      av1 = *(const int4*)(Arow + k0 + 8);
    }
    int4 bv0 = *(const int4*)(Brow + k0);
    int4 bv1 = *(const int4*)(Brow + k0 + 8);
    __syncthreads();
    *(int4*)&As[skc][srow][0]     = av0;
    *(int4*)&As[skc + 1][srow][0] = av1;
    *(int4*)&Bs[skc][srow][0]     = bv0;
    *(int4*)&Bs[skc + 1][srow][0] = bv1;
    __syncthreads();

    f16x8 af[4], bfr[4];
    #pragma unroll
    for (int m = 0; m < 4; ++m)  af[m]  = *(const f16x8*)&As[kc][wm + m * 16 + r16][0];
    #pragma unroll
    for (int n2 = 0; n2 < 4; ++n2) bfr[n2] = *(const f16x8*)&Bs[kc][wn + n2 * 16 + r16][0];
    #pragma unroll
    for (int m = 0; m < 4; ++m)
      #pragma unroll
      for (int n2 = 0; n2 < 4; ++n2)
        acc[m][n2] = __builtin_amdgcn_mfma_f32_16x16x32_f16(af[m], bfr[n2], acc[m][n2], 0, 0, 0);
  }

  int rq = lane >> 4;
  #pragma unroll
  for (int m = 0; m < 4; ++m) {
    #pragma unroll
    for (int r = 0; r < 4; ++r) {
      int row = bm + wm + m * 16 + rq * 4 + r;
      if (row < M) {
        #pragma unroll
        for (int n2 = 0; n2 < 4; ++n2) {
          int col = colZ + bn + wn + n2 * 16 + r16;
          float val = acc[m][n2][r];
          if (bias) val += bias[col];
          if (act)  val = eluf(val);
          C[(size_t)row * Nc + col] = f2h(val);
        }
      }
    }
  }
}

// ---------- 5. layer-2 attention logits from f16 H2 ----------
__global__ __launch_bounds__(128)
void logits2_kernel(const unsigned short* __restrict__ H,
                    const float* __restrict__ a_s, const float* __restrict__ a_d,
                    float* __restrict__ al_s, float* __restrict__ al_d, int N)
{
  int n = blockIdx.x, t = threadIdx.x;
  int wv = t >> 6, lane = t & 63;
  __shared__ float tmp[2][2];
  float hv = h2f(H[(size_t)n * HC + t]);
  float ps = hv * a_s[t];
  float pd = hv * a_d[t];
  #pragma unroll
  for (int off = 32; off; off >>= 1) { ps += __shfl_down(ps, off); pd += __shfl_down(pd, off); }
  if (lane == 0) { tmp[0][wv] = ps; tmp[1][wv] = pd; }
  __syncthreads();
  if (t == 0) {
    al_s[n] = tmp[0][0] + tmp[0][1];
    al_d[n] = tmp[1][0] + tmp[1][1];
  }
}

// ---------- 6. layer-2 aggregation; 4 waves/block + readlane broadcast ----------
__global__ __launch_bounds__(256)
void agg_h2_kernel(const unsigned short* __restrict__ H,
                   const float* __restrict__ al_s, const float* __restrict__ al_d,
                   const int* __restrict__ rowptr, const int* __restrict__ csr_src,
                   const float* __restrict__ bias, unsigned short* __restrict__ out, int N)
{
  int wv = threadIdx.x >> 6, lane = threadIdx.x & 63;
  int n = blockIdx.x * 4 + wv;
  if (n >= N) return;
  int rs = __builtin_amdgcn_readfirstlane(rowptr[n]);
  int re = __builtin_amdgcn_readfirstlane(rowptr[n + 1]);
  float ald = al_d[n];

  float m = -1e30f, s = 0.f;
  for (int i = rs + lane; i < re; i += 64) {
    int src = csr_src[i];
    float e = leaky02(al_s[src] + ald);
    float Mx = fmaxf(m, e);
    s = s * __expf(m - Mx) + __expf(e - Mx);
    m = Mx;
  }
  #pragma unroll
  for (int off = 32; off; off >>= 1) {
    float m2 = __shfl_down(m, off);
    float s2 = __shfl_down(s, off);
    float Mx = fmaxf(m, m2);
    s = s * __expf(m - Mx) + s2 * __expf(m2 - Mx);
    m = Mx;
  }
  m = __shfl(m, 0);
  s = __shfl(s, 0);
  float inv_den = 1.f / (s + 1e-16f);

  float acc0 = 0.f, acc1 = 0.f;
  for (int c0 = rs; c0 < re; c0 += 64) {
    int cnt = min(64, re - c0);
    int srcA = 0;
    float eA = 0.f;
    if (lane < cnt) {
      srcA = csr_src[c0 + lane];
      eA = __expf(leaky02(al_s[srcA] + ald) - m) * inv_den;
    }
    for (int j = 0; j < cnt; ++j) {
      int src = __builtin_amdgcn_readlane(srcA, j);
      float wgt = readlane_f(eA, j);
      ushort2 v = *(const ushort2*)&H[(size_t)src * HC + 2 * lane];
      acc0 += wgt * h2f(v.x);
      acc1 += wgt * h2f(v.y);
    }
  }
  float o0 = eluf(acc0 + bias[2 * lane]);
  float o1 = eluf(acc1 + bias[2 * lane + 1]);
  ushort2 o; o.x = f2h(o0); o.y = f2h(o1);
  *(ushort2*)&out[(size_t)n * HC + 2 * lane] = o;
}

// ---------- 7. global max pool (segmented over sorted batch) ----------
static __device__ __forceinline__ unsigned enc_f(float f)
{
  unsigned u = __float_as_uint(f);
  return (u & 0x80000000u) ? ~u : (u | 0x80000000u);
}
static __device__ __forceinline__ float dec_f(unsigned u)
{
  return (u & 0x80000000u) ? __uint_as_float(u & 0x7fffffffu) : __uint_as_float(~u);
}

__global__ void pool_init_kernel(unsigned* __restrict__ p, int n)
{
  int i = blockIdx.x * blockDim.x + threadIdx.x;
  if (i < n) p[i] = 0x00800000u;  // enc(-FLT_MAX)
}

#define PNPB 128   // nodes per pool block
__global__ __launch_bounds__(256)
void pool_seg_kernel(const unsigned short* __restrict__ x, const int* __restrict__ batch,
                     unsigned* __restrict__ pool, int N)
{
  int cp = (threadIdx.x & 63) * 2;     // channel pair
  int g  = threadIdx.x >> 6;           // node group 0..3
  int n0 = blockIdx.x * PNPB;
  int n1 = min(n0 + PNPB, N);
  int curb = -1;
  float m0 = 0.f, m1 = 0.f;
  for (int n = n0 + g; n < n1; n += 4) {
    int bg = batch[n];
    ushort2 v = *(const ushort2*)&x[(size_t)n * HC + cp];
    float v0 = h2f(v.x), v1 = h2f(v.y);
    if (bg != curb) {
      if (curb >= 0) {
        atomicMax(&pool[curb * HC + cp],     enc_f(m0));
        atomicMax(&pool[curb * HC + cp + 1], enc_f(m1));
      }
      curb = bg; m0 = v0; m1 = v1;
    } else {
      m0 = fmaxf(m0, v0);
      m1 = fmaxf(m1, v1);
    }
  }
  if (curb >= 0) {
    atomicMax(&pool[curb * HC + cp],     enc_f(m0));
    atomicMax(&pool[curb * HC + cp + 1], enc_f(m1));
  }
}

__global__ void pool_final_kernel(const unsigned* __restrict__ pool, float* __restrict__ out, int n)
{
  int i = blockIdx.x * blockDim.x + threadIdx.x;
  if (i < n) out[i] = dec_f(pool[i]);
}

// ---------- launch ----------
extern "C" void kernel_launch(void* const* d_in, const int* in_sizes, int n_in,
                              void* d_out, int out_size, void* d_ws, size_t ws_size,
                              hipStream_t stream)
{
  const float* x_scalar = (const float*)d_in[0];
  const int* i0 = (const int*)d_in[1];
  const int* i1 = (const int*)d_in[2];
  const int* i2 = (const int*)d_in[3];
  const int* i3 = (const int*)d_in[4];
  const int* i4 = (const int*)d_in[5];
  const int* ei = (const int*)d_in[6];
  const int* batch = (const int*)d_in[7];
  const float* e0 = (const float*)d_in[8];
  const float* e1 = (const float*)d_in[9];
  const float* e2 = (const float*)d_in[10];
  const float* e3 = (const float*)d_in[11];
  const float* e4 = (const float*)d_in[12];
  const float* ln_g = (const float*)d_in[13];
  const float* ln_b = (const float*)d_in[14];
  const float* W1 = (const float*)d_in[15];
  const float* as1 = (const float*)d_in[16];
  const float* ad1 = (const float*)d_in[17];
  const float* b1 = (const float*)d_in[18];
  const float* W2 = (const float*)d_in[19];
  const float* as2 = (const float*)d_in[20];
  const float* ad2 = (const float*)d_in[21];
  const float* b2 = (const float*)d_in[22];

  const int N  = in_sizes[0] / SF;
  const int E  = in_sizes[6] / 2;
  const int Et = E + N;
  const int Bg = out_size / HC;
  const int MT = (N + 127) / 128;

  char* w = (char*)d_ws;
  auto alloc = [&](size_t bytes) -> char* {
    char* p = w;
    w += (bytes + 255) & ~(size_t)255;
    return p;
  };
  unsigned short* featsb = (unsigned short*)alloc((size_t)N * KP1 * 2);
  unsigned short* G      = (unsigned short*)alloc((size_t)4 * N * KP1 * 2);
  unsigned short* X2b    = (unsigned short*)alloc((size_t)N * 512 * 2);
  unsigned short* H2b    = (unsigned short*)alloc((size_t)N * HC * 2);
  unsigned short* X3b    = (unsigned short*)alloc((size_t)N * HC * 2);
  unsigned short* W1t    = (unsigned short*)alloc((size_t)512 * KP1 * 2);
  unsigned short* W2t    = (unsigned short*)alloc((size_t)HC * 512 * 2);
  float* vs      = (float*)alloc((size_t)KP1 * 4 * 4);
  float* vd      = (float*)alloc((size_t)KP1 * 4 * 4);
  float* als1    = (float*)alloc((size_t)N * 4 * 4);
  float* ald1    = (float*)alloc((size_t)N * 4 * 4);
  float* als2    = (float*)alloc((size_t)N * 4);
  float* ald2    = (float*)alloc((size_t)N * 4);
  int*   deg     = (int*)alloc((size_t)N * 4);
  int*   rowptr  = (int*)alloc((size_t)(N + 1) * 4);
  int*   fill    = (int*)alloc((size_t)N * 4);
  int*   csr_src = (int*)alloc((size_t)Et * 4);
  unsigned* pool = (unsigned*)alloc((size_t)Bg * HC * 4);

  // constants per call
  pack_wt_kernel<<<(512 * KP1 + 255) / 256, 256, 0, stream>>>(W1, W1t, DIN, 512, KP1);
  pack_wt_kernel<<<(HC * 512 + 255) / 256, 256, 0, stream>>>(W2, W2t, 512, HC, 512);
  prep_attn_kernel<<<DIN, 256, 0, stream>>>(W1, as1, ad1, vs, vd);

  // features + LN + fused layer-1 logits (one wave per node, 4 nodes/block)
  feat_ln_kernel<<<(N + 3) / 4, 256, 0, stream>>>(x_scalar, i0, i1, i2, i3, i4,
                                                  e0, e1, e2, e3, e4, ln_g, ln_b,
                                                  (const float4*)vs, (const float4*)vd,
                                                  featsb, als1, ald1, N);

  // CSR
  zero_kernel<<<(N + 255) / 256, 256, 0, stream>>>(deg, N);
  count_kernel<<<(Et + 255) / 256, 256, 0, stream>>>(ei, E, N, deg);
  scan_kernel<<<1, 1024, 0, stream>>>(deg, rowptr, fill, N);
  scatter_kernel<<<(Et + 255) / 256, 256, 0, stream>>>(ei, E, N, fill, csr_src);

  // layer 1: aggregate feats (4 heads share gather), then per-head GEMM (+b1, ELU)
  agg_feat_kernel<<<(N + 3) / 4, 256, 0, stream>>>(featsb, (const float4*)als1,
                                                   (const float4*)ald1,
                                                   rowptr, csr_src, G, N);
  gemm_f16_kernel<KP1><<<dim3(1, MT, 4), 256, 0, stream>>>(
      G, W1t, X2b, N, 512, (size_t)N * KP1, (size_t)HC * KP1, HC, b1, 1);

  // layer 2: GEMM (raw H2), logits, aggregate (+b2, ELU)
  gemm_f16_kernel<512><<<dim3(1, MT, 1), 256, 0, stream>>>(
      X2b, W2t, H2b, N, HC, 0, 0, 0, nullptr, 0);
  logits2_kernel<<<N, 128, 0, stream>>>(H2b, as2, ad2, als2, ald2, N);
  agg_h2_kernel<<<(N + 3) / 4, 256, 0, stream>>>(H2b, als2, ald2, rowptr, csr_src, b2, X3b, N);

  // pool
  pool_init_kernel<<<(Bg * HC + 255) / 256, 256, 0, stream>>>(pool, Bg * HC);
  pool_seg_kernel<<<(N + PNPB - 1) / PNPB, 256, 0, stream>>>(X3b, batch, pool, N);
  pool_final_kernel<<<(Bg * HC + 255) / 256, 256, 0, stream>>>(pool, (float*)d_out, Bg * HC);
}

// Round 7
// 270.380 us; speedup vs baseline: 1.8726x; 1.0318x over previous
//
#include <hip/hip_runtime.h>
#include <math.h>

#define SF 16
#define ED 32
#define LTOK 20
#define DIN 176
#define KP1 192   // DIN padded to multiple of 32
#define HC 128

typedef _Float16 f16x8 __attribute__((ext_vector_type(8)));
typedef float f32x4 __attribute__((ext_vector_type(4)));

static __device__ __forceinline__ float leaky02(float x) { return x >= 0.f ? x : 0.2f * x; }
static __device__ __forceinline__ float eluf(float x)    { return x > 0.f ? x : expm1f(x); }
static __device__ __forceinline__ unsigned short f2h(float f)
{
  _Float16 h = (_Float16)f;
  return __builtin_bit_cast(unsigned short, h);
}
static __device__ __forceinline__ float h2f(unsigned short u)
{
  return (float)__builtin_bit_cast(_Float16, u);
}
static __device__ __forceinline__ float readlane_f(float v, int j)
{
  return __int_as_float(__builtin_amdgcn_readlane(__float_as_int(v), j));
}

// ---------- 0a. pack W [K][Nc] fp32 -> Wt [Nc][KPad] f16 (zero pad) ----------
__global__ void pack_wt_kernel(const float* __restrict__ W, unsigned short* __restrict__ Wt,
                               int K, int Nc, int KPad)
{
  int i = blockIdx.x * blockDim.x + threadIdx.x;
  if (i < Nc * KPad) {
    int n = i / KPad;
    int k = i - n * KPad;
    float v = (k < K) ? W[(size_t)k * Nc + n] : 0.f;
    Wt[i] = f2h(v);
  }
}

// ---------- 0b. v_s[k][h] = sum_c W1[k][h*128+c]*a_s[h][c] (and v_d) ----------
__global__ __launch_bounds__(256)
void prep_attn_kernel(const float* __restrict__ W1, const float* __restrict__ as1,
                      const float* __restrict__ ad1,
                      float* __restrict__ vs, float* __restrict__ vd)
{
  int k = blockIdx.x;                 // 0..175
  int h = threadIdx.x >> 6, lane = threadIdx.x & 63;
  const float* row = W1 + (size_t)k * 512 + h * HC;
  float s = row[lane] * as1[h * HC + lane] + row[lane + 64] * as1[h * HC + lane + 64];
  float d = row[lane] * ad1[h * HC + lane] + row[lane + 64] * ad1[h * HC + lane + 64];
  #pragma unroll
  for (int off = 32; off; off >>= 1) { s += __shfl_down(s, off); d += __shfl_down(d, off); }
  if (lane == 0) { vs[k * 4 + h] = s; vd[k * 4 + h] = d; }
}

// ---------- 1. features + LayerNorm + fused logits; ONE WAVE PER NODE ----------
__global__ __launch_bounds__(256)
void feat_ln_kernel(const float* __restrict__ xs,
                    const int* __restrict__ i0, const int* __restrict__ i1,
                    const int* __restrict__ i2, const int* __restrict__ i3,
                    const int* __restrict__ i4,
                    const float* __restrict__ e0, const float* __restrict__ e1,
                    const float* __restrict__ e2, const float* __restrict__ e3,
                    const float* __restrict__ e4,
                    const float* __restrict__ g, const float* __restrict__ b,
                    const float4* __restrict__ vs, const float4* __restrict__ vd,
                    unsigned short* __restrict__ out,
                    float* __restrict__ als, float* __restrict__ ald, int N)
{
  __shared__ int toks[4][5 * LTOK];
  int w = threadIdx.x >> 6, l = threadIdx.x & 63;
  int n = blockIdx.x * 4 + w;
  if (n >= N) return;

  for (int q = l; q < 5 * LTOK; q += 64) {
    int f = q / LTOK, j = q - f * LTOK;
    const int* ip = (f == 0) ? i0 : (f == 1) ? i1 : (f == 2) ? i2 : (f == 3) ? i3 : i4;
    toks[w][q] = ip[n * LTOK + j];
  }

  float v[3];
  #pragma unroll
  for (int r = 0; r < 3; ++r) {
    int c = l + r * 64;
    float val = 0.f;
    if (c < SF) {
      val = xs[n * SF + c];
    } else if (c < DIN) {
      int f  = (c - SF) >> 5;
      int ch = (c - SF) & 31;
      const float* ep = (f == 0) ? e0 : (f == 1) ? e1 : (f == 2) ? e2 : (f == 3) ? e3 : e4;
      float vals[LTOK];
      #pragma unroll
      for (int j = 0; j < LTOK; ++j)
        vals[j] = ep[toks[w][f * LTOK + j] * ED + ch];
      float sum = 0.f, cnt = 0.f;
      #pragma unroll
      for (int j = 0; j < LTOK; ++j)
        if (toks[w][f * LTOK + j] != 0) { sum += vals[j]; cnt += 1.f; }
      val = sum / (cnt + 1e-9f);
    }
    v[r] = val;
  }

  float p  = v[0] + v[1] + v[2];
  float p2 = v[0] * v[0] + v[1] * v[1] + v[2] * v[2];
  #pragma unroll
  for (int off = 32; off; off >>= 1) { p += __shfl_xor(p, off); p2 += __shfl_xor(p2, off); }
  float mu   = p * (1.f / DIN);
  float var  = fmaxf(p2 * (1.f / DIN) - mu * mu, 0.f);
  float rstd = rsqrtf(var + 1e-5f);

  float pr[8] = {0.f, 0.f, 0.f, 0.f, 0.f, 0.f, 0.f, 0.f};
  #pragma unroll
  for (int r = 0; r < 3; ++r) {
    int c = l + r * 64;
    float y = 0.f;
    if (c < DIN) {
      y = (v[r] - mu) * rstd * g[c] + b[c];
      float4 s4 = vs[c], d4 = vd[c];
      pr[0] += y * s4.x; pr[1] += y * s4.y; pr[2] += y * s4.z; pr[3] += y * s4.w;
      pr[4] += y * d4.x; pr[5] += y * d4.y; pr[6] += y * d4.z; pr[7] += y * d4.w;
    }
    if (c < KP1) out[(size_t)n * KP1 + c] = f2h(y);
  }
  #pragma unroll
  for (int j = 0; j < 8; ++j)
    #pragma unroll
    for (int off = 32; off; off >>= 1) pr[j] += __shfl_xor(pr[j], off);
  if (l == 0) {
    als[n * 4 + 0] = pr[0]; als[n * 4 + 1] = pr[1];
    als[n * 4 + 2] = pr[2]; als[n * 4 + 3] = pr[3];
    ald[n * 4 + 0] = pr[4]; ald[n * 4 + 1] = pr[5];
    ald[n * 4 + 2] = pr[6]; ald[n * 4 + 3] = pr[7];
  }
}

// ---------- 2. CSR build ----------
__global__ void zero_kernel(int* __restrict__ p, int n)
{
  int i = blockIdx.x * blockDim.x + threadIdx.x;
  if (i < n) p[i] = 0;
}

__global__ void count_kernel(const int* __restrict__ ei, int E, int N, int* __restrict__ deg)
{
  int e = blockIdx.x * blockDim.x + threadIdx.x;
  if (e < E + N) {
    int dst = (e < E) ? ei[E + e] : (e - E);
    atomicAdd(&deg[dst], 1);
  }
}

__global__ __launch_bounds__(1024)
void scan_kernel(const int* __restrict__ deg, int* __restrict__ rowptr,
                 int* __restrict__ fill, int N)
{
  __shared__ int sums[1024];
  int t = threadIdx.x;
  int CH = (N + 1023) >> 10;
  int base = t * CH;
  int s = 0;
  for (int i = 0; i < CH; ++i) if (base + i < N) s += deg[base + i];
  sums[t] = s;
  __syncthreads();
  for (int off = 1; off < 1024; off <<= 1) {
    int v = (t >= off) ? sums[t - off] : 0;
    __syncthreads();
    sums[t] += v;
    __syncthreads();
  }
  int run = sums[t] - s;  // exclusive prefix
  for (int i = 0; i < CH; ++i) {
    if (base + i < N) {
      rowptr[base + i] = run;
      fill[base + i]   = run;
      run += deg[base + i];
    }
  }
  if (t == 1023) rowptr[N] = run;
}

__global__ void scatter_kernel(const int* __restrict__ ei, int E, int N,
                               int* __restrict__ fill, int* __restrict__ csr_src)
{
  int e = blockIdx.x * blockDim.x + threadIdx.x;
  if (e < E + N) {
    int src, dst;
    if (e < E) { src = ei[e]; dst = ei[E + e]; }
    else       { src = dst = e - E; }
    int pos = atomicAdd(&fill[dst], 1);
    csr_src[pos] = src;
  }
}

// ---------- pass B helper: 2 edges/iter, halves combine later ----------
// half = lane>>5, sub = lane&31; lanes sub<24 carry 8 channels each (16B).
static __device__ __forceinline__ void agg_passB(
    const unsigned short* __restrict__ F, int cnt, int srcA, float4 wA,
    int half, int sub, float acc[4][8])
{
  for (int j = 0; j < cnt; j += 2) {
    int j1 = j + 1;
    bool has1 = j1 < cnt;             // wave-uniform
    int s0 = __builtin_amdgcn_readlane(srcA, j);
    int s1 = has1 ? __builtin_amdgcn_readlane(srcA, j1) : s0;
    float w[4];
    float w0x = readlane_f(wA.x, j), w0y = readlane_f(wA.y, j);
    float w0z = readlane_f(wA.z, j), w0w = readlane_f(wA.w, j);
    float w1x = 0.f, w1y = 0.f, w1z = 0.f, w1w = 0.f;
    if (has1) {
      w1x = readlane_f(wA.x, j1); w1y = readlane_f(wA.y, j1);
      w1z = readlane_f(wA.z, j1); w1w = readlane_f(wA.w, j1);
    }
    w[0] = half ? w1x : w0x;  w[1] = half ? w1y : w0y;
    w[2] = half ? w1z : w0z;  w[3] = half ? w1w : w0w;
    int src = half ? s1 : s0;
    if (sub < 24) {
      int4 vv = *(const int4*)(F + (size_t)src * KP1 + sub * 8);
      float f[8];
      f[0] = h2f((unsigned short)(vv.x & 0xffff)); f[1] = h2f((unsigned short)((unsigned)vv.x >> 16));
      f[2] = h2f((unsigned short)(vv.y & 0xffff)); f[3] = h2f((unsigned short)((unsigned)vv.y >> 16));
      f[4] = h2f((unsigned short)(vv.z & 0xffff)); f[5] = h2f((unsigned short)((unsigned)vv.z >> 16));
      f[6] = h2f((unsigned short)(vv.w & 0xffff)); f[7] = h2f((unsigned short)((unsigned)vv.w >> 16));
      #pragma unroll
      for (int h = 0; h < 4; ++h)
        #pragma unroll
        for (int c = 0; c < 8; ++c)
          acc[h][c] += w[h] * f[c];
    }
  }
}

// ---------- 3. layer-1 aggregation over FEATURES ----------
// 4 waves/block (one node per wave). Single-chunk fast path (deg<=64):
// lane j owns edge j -> direct butterfly softmax, no streaming pass.
__global__ __launch_bounds__(256)
void agg_feat_kernel(const unsigned short* __restrict__ F,   // [N][KP1] f16
                     const float4* __restrict__ als, const float4* __restrict__ ald,
                     const int* __restrict__ rowptr, const int* __restrict__ csr_src,
                     unsigned short* __restrict__ G, int N)  // [4][N][KP1] f16
{
  int wv = threadIdx.x >> 6, lane = threadIdx.x & 63;
  int n = blockIdx.x * 4 + wv;
  if (n >= N) return;
  int rs = __builtin_amdgcn_readfirstlane(rowptr[n]);
  int re = __builtin_amdgcn_readfirstlane(rowptr[n + 1]);
  int cnt = re - rs;
  float4 ad4 = ald[n];
  float aldv[4] = { ad4.x, ad4.y, ad4.z, ad4.w };
  int half = lane >> 5, sub = lane & 31;
  float acc[4][8] = {};

  if (cnt <= 64) {
    // ---- fast path: one edge per lane ----
    int srcA = 0;
    float e[4] = { -1e30f, -1e30f, -1e30f, -1e30f };
    if (lane < cnt) {
      srcA = csr_src[rs + lane];
      float4 a4 = als[srcA];
      e[0] = leaky02(a4.x + aldv[0]); e[1] = leaky02(a4.y + aldv[1]);
      e[2] = leaky02(a4.z + aldv[2]); e[3] = leaky02(a4.w + aldv[3]);
    }
    float m[4] = { e[0], e[1], e[2], e[3] };
    #pragma unroll
    for (int off = 32; off; off >>= 1)
      #pragma unroll
      for (int h = 0; h < 4; ++h) m[h] = fmaxf(m[h], __shfl_xor(m[h], off));
    float ex[4];
    #pragma unroll
    for (int h = 0; h < 4; ++h) ex[h] = (lane < cnt) ? __expf(e[h] - m[h]) : 0.f;
    float den[4] = { ex[0], ex[1], ex[2], ex[3] };
    #pragma unroll
    for (int off = 32; off; off >>= 1)
      #pragma unroll
      for (int h = 0; h < 4; ++h) den[h] += __shfl_xor(den[h], off);
    float4 wA;
    wA.x = ex[0] / (den[0] + 1e-16f); wA.y = ex[1] / (den[1] + 1e-16f);
    wA.z = ex[2] / (den[2] + 1e-16f); wA.w = ex[3] / (den[3] + 1e-16f);
    agg_passB(F, cnt, srcA, wA, half, sub, acc);
  } else {
    // ---- slow path: streaming online softmax, then chunked ----
    float m[4], s[4];
    #pragma unroll
    for (int h = 0; h < 4; ++h) { m[h] = -1e30f; s[h] = 0.f; }
    for (int i = rs + lane; i < re; i += 64) {
      int src = csr_src[i];
      float4 a4 = als[src];
      float av[4] = { a4.x, a4.y, a4.z, a4.w };
      #pragma unroll
      for (int h = 0; h < 4; ++h) {
        float e = leaky02(av[h] + aldv[h]);
        float Mx = fmaxf(m[h], e);
        s[h] = s[h] * __expf(m[h] - Mx) + __expf(e - Mx);
        m[h] = Mx;
      }
    }
    #pragma unroll
    for (int off = 32; off; off >>= 1) {
      #pragma unroll
      for (int h = 0; h < 4; ++h) {
        float m2 = __shfl_xor(m[h], off);
        float s2 = __shfl_xor(s[h], off);
        float Mx = fmaxf(m[h], m2);
        s[h] = s[h] * __expf(m[h] - Mx) + s2 * __expf(m2 - Mx);
        m[h] = Mx;
      }
    }
    float inv[4];
    #pragma unroll
    for (int h = 0; h < 4; ++h) inv[h] = 1.f / (s[h] + 1e-16f);
    for (int c0 = rs; c0 < re; c0 += 64) {
      int ccnt = min(64, re - c0);
      int srcA = 0;
      float4 wA = make_float4(0.f, 0.f, 0.f, 0.f);
      if (lane < ccnt) {
        srcA = csr_src[c0 + lane];
        float4 a4 = als[srcA];
        wA.x = __expf(leaky02(a4.x + aldv[0]) - m[0]) * inv[0];
        wA.y = __expf(leaky02(a4.y + aldv[1]) - m[1]) * inv[1];
        wA.z = __expf(leaky02(a4.z + aldv[2]) - m[2]) * inv[2];
        wA.w = __expf(leaky02(a4.w + aldv[3]) - m[3]) * inv[3];
      }
      agg_passB(F, ccnt, srcA, wA, half, sub, acc);
    }
  }

  // combine halves; lanes 0..23 write 8 channels each
  #pragma unroll
  for (int h = 0; h < 4; ++h)
    #pragma unroll
    for (int c = 0; c < 8; ++c)
      acc[h][c] += __shfl_xor(acc[h][c], 32);
  if (lane < 24) {
    #pragma unroll
    for (int h = 0; h < 4; ++h) {
      int4 o;
      o.x = (int)f2h(acc[h][0]) | ((int)f2h(acc[h][1]) << 16);
      o.y = (int)f2h(acc[h][2]) | ((int)f2h(acc[h][3]) << 16);
      o.z = (int)f2h(acc[h][4]) | ((int)f2h(acc[h][5]) << 16);
      o.w = (int)f2h(acc[h][6]) | ((int)f2h(acc[h][7]) << 16);
      *(int4*)&G[((size_t)h * N + n) * KP1 + lane * 8] = o;
    }
  }
}

// ---------- 4. MFMA f16 GEMM: C[:, zcols] = A_z[M,KPad] @ Bt_z[128,KPad]^T (+bias, ELU) ----------
template<int KPad>
__global__ __launch_bounds__(256)
void gemm_f16_kernel(const unsigned short* __restrict__ A, const unsigned short* __restrict__ Bt,
                     unsigned short* __restrict__ C, int M, int Nc,
                     size_t aStrideZ, size_t bStrideZ, int cColStrideZ,
                     const float* __restrict__ bias, int act)
{
  A  += blockIdx.z * aStrideZ;
  Bt += blockIdx.z * bStrideZ;
  int colZ = blockIdx.z * cColStrideZ;

  __shared__ __align__(16) unsigned short As[4][128][8];
  __shared__ __align__(16) unsigned short Bs[4][128][8];
  int tid  = threadIdx.x;
  int lane = tid & 63, wave = tid >> 6;
  int wm = (wave >> 1) << 6, wn = (wave & 1) << 6;
  int bm = blockIdx.y << 7, bn = blockIdx.x << 7;

  int srow = tid >> 1;
  int skc  = (tid & 1) << 1;
  const unsigned short* Arow = A  + (size_t)(bm + srow) * KPad + skc * 8;
  const unsigned short* Brow = Bt + (size_t)(bn + srow) * KPad + skc * 8;
  bool aok = (bm + srow) < M;

  f32x4 acc[4][4];
  #pragma unroll
  for (int m = 0; m < 4; ++m)
    #pragma unroll
    for (int n2 = 0; n2 < 4; ++n2) acc[m][n2] = (f32x4){0.f, 0.f, 0.f, 0.f};

  int kc  = lane >> 4;
  int r16 = lane & 15;

  for (int k0 = 0; k0 < KPad; k0 += 32) {
    int4 av0 = make_int4(0, 0, 0, 0), av1 = make_int4(0, 0, 0, 0);
    if (aok) {
      av0 = *(const int4*)(Arow + k0);
      av1 = *(const int4*)(Arow + k0 + 8);
    }
    int4 bv0 = *(const int4*)(Brow + k0);
    int4 bv1 = *(const int4*)(Brow + k0 + 8);
    __syncthreads();
    *(int4*)&As[skc][srow][0]     = av0;
    *(int4*)&As[skc + 1][srow][0] = av1;
    *(int4*)&Bs[skc][srow][0]     = bv0;
    *(int4*)&Bs[skc + 1][srow][0] = bv1;
    __syncthreads();

    f16x8 af[4], bfr[4];
    #pragma unroll
    for (int m = 0; m < 4; ++m)  af[m]  = *(const f16x8*)&As[kc][wm + m * 16 + r16][0];
    #pragma unroll
    for (int n2 = 0; n2 < 4; ++n2) bfr[n2] = *(const f16x8*)&Bs[kc][wn + n2 * 16 + r16][0];
    #pragma unroll
    for (int m = 0; m < 4; ++m)
      #pragma unroll
      for (int n2 = 0; n2 < 4; ++n2)
        acc[m][n2] = __builtin_amdgcn_mfma_f32_16x16x32_f16(af[m], bfr[n2], acc[m][n2], 0, 0, 0);
  }

  int rq = lane >> 4;
  #pragma unroll
  for (int m = 0; m < 4; ++m) {
    #pragma unroll
    for (int r = 0; r < 4; ++r) {
      int row = bm + wm + m * 16 + rq * 4 + r;
      if (row < M) {
        #pragma unroll
        for (int n2 = 0; n2 < 4; ++n2) {
          int col = colZ + bn + wn + n2 * 16 + r16;
          float val = acc[m][n2][r];
          if (bias) val += bias[col];
          if (act)  val = eluf(val);
          C[(size_t)row * Nc + col] = f2h(val);
        }
      }
    }
  }
}

// ---------- 5. layer-2 attention logits from f16 H2 ----------
__global__ __launch_bounds__(128)
void logits2_kernel(const unsigned short* __restrict__ H,
                    const float* __restrict__ a_s, const float* __restrict__ a_d,
                    float* __restrict__ al_s, float* __restrict__ al_d, int N)
{
  int n = blockIdx.x, t = threadIdx.x;
  int wv = t >> 6, lane = t & 63;
  __shared__ float tmp[2][2];
  float hv = h2f(H[(size_t)n * HC + t]);
  float ps = hv * a_s[t];
  float pd = hv * a_d[t];
  #pragma unroll
  for (int off = 32; off; off >>= 1) { ps += __shfl_down(ps, off); pd += __shfl_down(pd, off); }
  if (lane == 0) { tmp[0][wv] = ps; tmp[1][wv] = pd; }
  __syncthreads();
  if (t == 0) {
    al_s[n] = tmp[0][0] + tmp[0][1];
    al_d[n] = tmp[1][0] + tmp[1][1];
  }
}

// ---------- 6. layer-2 aggregation; fast-path softmax + 2-edge pass B ----------
__global__ __launch_bounds__(256)
void agg_h2_kernel(const unsigned short* __restrict__ H,
                   const float* __restrict__ al_s, const float* __restrict__ al_d,
                   const int* __restrict__ rowptr, const int* __restrict__ csr_src,
                   const float* __restrict__ bias, unsigned short* __restrict__ out, int N)
{
  int wv = threadIdx.x >> 6, lane = threadIdx.x & 63;
  int n = blockIdx.x * 4 + wv;
  if (n >= N) return;
  int rs = __builtin_amdgcn_readfirstlane(rowptr[n]);
  int re = __builtin_amdgcn_readfirstlane(rowptr[n + 1]);
  int cnt = re - rs;
  float ald = al_d[n];
  int half = lane >> 5, sub = lane & 31;
  float acc[4] = {0.f, 0.f, 0.f, 0.f};

  auto passB = [&](int c2, int srcA, float wAl) {
    for (int j = 0; j < c2; j += 2) {
      int j1 = j + 1;
      bool has1 = j1 < c2;
      int s0 = __builtin_amdgcn_readlane(srcA, j);
      int s1 = has1 ? __builtin_amdgcn_readlane(srcA, j1) : s0;
      float w0 = readlane_f(wAl, j);
      float w1 = has1 ? readlane_f(wAl, j1) : 0.f;
      float wgt = half ? w1 : w0;
      int src = half ? s1 : s0;
      int2 vv = *(const int2*)(H + (size_t)src * HC + sub * 4);
      acc[0] += wgt * h2f((unsigned short)(vv.x & 0xffff));
      acc[1] += wgt * h2f((unsigned short)((unsigned)vv.x >> 16));
      acc[2] += wgt * h2f((unsigned short)(vv.y & 0xffff));
      acc[3] += wgt * h2f((unsigned short)((unsigned)vv.y >> 16));
    }
  };

  if (cnt <= 64) {
    int srcA = 0;
    float e = -1e30f;
    if (lane < cnt) {
      srcA = csr_src[rs + lane];
      e = leaky02(al_s[srcA] + ald);
    }
    float m = e;
    #pragma unroll
    for (int off = 32; off; off >>= 1) m = fmaxf(m, __shfl_xor(m, off));
    float ex = (lane < cnt) ? __expf(e - m) : 0.f;
    float den = ex;
    #pragma unroll
    for (int off = 32; off; off >>= 1) den += __shfl_xor(den, off);
    passB(cnt, srcA, ex / (den + 1e-16f));
  } else {
    float m = -1e30f, s = 0.f;
    for (int i = rs + lane; i < re; i += 64) {
      int src = csr_src[i];
      float e = leaky02(al_s[src] + ald);
      float Mx = fmaxf(m, e);
      s = s * __expf(m - Mx) + __expf(e - Mx);
      m = Mx;
    }
    #pragma unroll
    for (int off = 32; off; off >>= 1) {
      float m2 = __shfl_xor(m, off);
      float s2 = __shfl_xor(s, off);
      float Mx = fmaxf(m, m2);
      s = s * __expf(m - Mx) + s2 * __expf(m2 - Mx);
      m = Mx;
    }
    float inv_den = 1.f / (s + 1e-16f);
    for (int c0 = rs; c0 < re; c0 += 64) {
      int ccnt = min(64, re - c0);
      int srcA = 0;
      float wAl = 0.f;
      if (lane < ccnt) {
        srcA = csr_src[c0 + lane];
        wAl = __expf(leaky02(al_s[srcA] + ald) - m) * inv_den;
      }
      passB(ccnt, srcA, wAl);
    }
  }

  #pragma unroll
  for (int c = 0; c < 4; ++c) acc[c] += __shfl_xor(acc[c], 32);
  if (lane < 32) {
    float o0 = eluf(acc[0] + bias[sub * 4 + 0]);
    float o1 = eluf(acc[1] + bias[sub * 4 + 1]);
    float o2 = eluf(acc[2] + bias[sub * 4 + 2]);
    float o3 = eluf(acc[3] + bias[sub * 4 + 3]);
    int2 o;
    o.x = (int)f2h(o0) | ((int)f2h(o1) << 16);
    o.y = (int)f2h(o2) | ((int)f2h(o3) << 16);
    *(int2*)&out[(size_t)n * HC + sub * 4] = o;
  }
}

// ---------- 7. global max pool (segmented over sorted batch) ----------
static __device__ __forceinline__ unsigned enc_f(float f)
{
  unsigned u = __float_as_uint(f);
  return (u & 0x80000000u) ? ~u : (u | 0x80000000u);
}
static __device__ __forceinline__ float dec_f(unsigned u)
{
  return (u & 0x80000000u) ? __uint_as_float(u & 0x7fffffffu) : __uint_as_float(~u);
}

__global__ void pool_init_kernel(unsigned* __restrict__ p, int n)
{
  int i = blockIdx.x * blockDim.x + threadIdx.x;
  if (i < n) p[i] = 0x00800000u;  // enc(-FLT_MAX)
}

#define PNPB 128   // nodes per pool block
__global__ __launch_bounds__(256)
void pool_seg_kernel(const unsigned short* __restrict__ x, const int* __restrict__ batch,
                     unsigned* __restrict__ pool, int N)
{
  int cp = (threadIdx.x & 63) * 2;     // channel pair
  int g  = threadIdx.x >> 6;           // node group 0..3
  int n0 = blockIdx.x * PNPB;
  int n1 = min(n0 + PNPB, N);
  int curb = -1;
  float m0 = 0.f, m1 = 0.f;
  for (int n = n0 + g; n < n1; n += 4) {
    int bg = batch[n];
    ushort2 v = *(const ushort2*)&x[(size_t)n * HC + cp];
    float v0 = h2f(v.x), v1 = h2f(v.y);
    if (bg != curb) {
      if (curb >= 0) {
        atomicMax(&pool[curb * HC + cp],     enc_f(m0));
        atomicMax(&pool[curb * HC + cp + 1], enc_f(m1));
      }
      curb = bg; m0 = v0; m1 = v1;
    } else {
      m0 = fmaxf(m0, v0);
      m1 = fmaxf(m1, v1);
    }
  }
  if (curb >= 0) {
    atomicMax(&pool[curb * HC + cp],     enc_f(m0));
    atomicMax(&pool[curb * HC + cp + 1], enc_f(m1));
  }
}

__global__ void pool_final_kernel(const unsigned* __restrict__ pool, float* __restrict__ out, int n)
{
  int i = blockIdx.x * blockDim.x + threadIdx.x;
  if (i < n) out[i] = dec_f(pool[i]);
}

// ---------- launch ----------
extern "C" void kernel_launch(void* const* d_in, const int* in_sizes, int n_in,
                              void* d_out, int out_size, void* d_ws, size_t ws_size,
                              hipStream_t stream)
{
  const float* x_scalar = (const float*)d_in[0];
  const int* i0 = (const int*)d_in[1];
  const int* i1 = (const int*)d_in[2];
  const int* i2 = (const int*)d_in[3];
  const int* i3 = (const int*)d_in[4];
  const int* i4 = (const int*)d_in[5];
  const int* ei = (const int*)d_in[6];
  const int* batch = (const int*)d_in[7];
  const float* e0 = (const float*)d_in[8];
  const float* e1 = (const float*)d_in[9];
  const float* e2 = (const float*)d_in[10];
  const float* e3 = (const float*)d_in[11];
  const float* e4 = (const float*)d_in[12];
  const float* ln_g = (const float*)d_in[13];
  const float* ln_b = (const float*)d_in[14];
  const float* W1 = (const float*)d_in[15];
  const float* as1 = (const float*)d_in[16];
  const float* ad1 = (const float*)d_in[17];
  const float* b1 = (const float*)d_in[18];
  const float* W2 = (const float*)d_in[19];
  const float* as2 = (const float*)d_in[20];
  const float* ad2 = (const float*)d_in[21];
  const float* b2 = (const float*)d_in[22];

  const int N  = in_sizes[0] / SF;
  const int E  = in_sizes[6] / 2;
  const int Et = E + N;
  const int Bg = out_size / HC;
  const int MT = (N + 127) / 128;

  char* w = (char*)d_ws;
  auto alloc = [&](size_t bytes) -> char* {
    char* p = w;
    w += (bytes + 255) & ~(size_t)255;
    return p;
  };
  unsigned short* featsb = (unsigned short*)alloc((size_t)N * KP1 * 2);
  unsigned short* G      = (unsigned short*)alloc((size_t)4 * N * KP1 * 2);
  unsigned short* X2b    = (unsigned short*)alloc((size_t)N * 512 * 2);
  unsigned short* H2b    = (unsigned short*)alloc((size_t)N * HC * 2);
  unsigned short* X3b    = (unsigned short*)alloc((size_t)N * HC * 2);
  unsigned short* W1t    = (unsigned short*)alloc((size_t)512 * KP1 * 2);
  unsigned short* W2t    = (unsigned short*)alloc((size_t)HC * 512 * 2);
  float* vs      = (float*)alloc((size_t)KP1 * 4 * 4);
  float* vd      = (float*)alloc((size_t)KP1 * 4 * 4);
  float* als1    = (float*)alloc((size_t)N * 4 * 4);
  float* ald1    = (float*)alloc((size_t)N * 4 * 4);
  float* als2    = (float*)alloc((size_t)N * 4);
  float* ald2    = (float*)alloc((size_t)N * 4);
  int*   deg     = (int*)alloc((size_t)N * 4);
  int*   rowptr  = (int*)alloc((size_t)(N + 1) * 4);
  int*   fill    = (int*)alloc((size_t)N * 4);
  int*   csr_src = (int*)alloc((size_t)Et * 4);
  unsigned* pool = (unsigned*)alloc((size_t)Bg * HC * 4);

  // constants per call
  pack_wt_kernel<<<(512 * KP1 + 255) / 256, 256, 0, stream>>>(W1, W1t, DIN, 512, KP1);
  pack_wt_kernel<<<(HC * 512 + 255) / 256, 256, 0, stream>>>(W2, W2t, 512, HC, 512);
  prep_attn_kernel<<<DIN, 256, 0, stream>>>(W1, as1, ad1, vs, vd);

  // features + LN + fused layer-1 logits (one wave per node, 4 nodes/block)
  feat_ln_kernel<<<(N + 3) / 4, 256, 0, stream>>>(x_scalar, i0, i1, i2, i3, i4,
                                                  e0, e1, e2, e3, e4, ln_g, ln_b,
                                                  (const float4*)vs, (const float4*)vd,
                                                  featsb, als1, ald1, N);

  // CSR
  zero_kernel<<<(N + 255) / 256, 256, 0, stream>>>(deg, N);
  count_kernel<<<(Et + 255) / 256, 256, 0, stream>>>(ei, E, N, deg);
  scan_kernel<<<1, 1024, 0, stream>>>(deg, rowptr, fill, N);
  scatter_kernel<<<(Et + 255) / 256, 256, 0, stream>>>(ei, E, N, fill, csr_src);

  // layer 1: aggregate feats (4 heads share gather), then per-head GEMM (+b1, ELU)
  agg_feat_kernel<<<(N + 3) / 4, 256, 0, stream>>>(featsb, (const float4*)als1,
                                                   (const float4*)ald1,
                                                   rowptr, csr_src, G, N);
  gemm_f16_kernel<KP1><<<dim3(1, MT, 4), 256, 0, stream>>>(
      G, W1t, X2b, N, 512, (size_t)N * KP1, (size_t)HC * KP1, HC, b1, 1);

  // layer 2: GEMM (raw H2), logits, aggregate (+b2, ELU)
  gemm_f16_kernel<512><<<dim3(1, MT, 1), 256, 0, stream>>>(
      X2b, W2t, H2b, N, HC, 0, 0, 0, nullptr, 0);
  logits2_kernel<<<N, 128, 0, stream>>>(H2b, as2, ad2, als2, ald2, N);
  agg_h2_kernel<<<(N + 3) / 4, 256, 0, stream>>>(H2b, als2, ald2, rowptr, csr_src, b2, X3b, N);

  // pool
  pool_init_kernel<<<(Bg * HC + 255) / 256, 256, 0, stream>>>(pool, Bg * HC);
  pool_seg_kernel<<<(N + PNPB - 1) / PNPB, 256, 0, stream>>>(X3b, batch, pool, N);
  pool_final_kernel<<<(Bg * HC + 255) / 256, 256, 0, stream>>>(pool, (float*)d_out, Bg * HC);
}